// Round 9
// baseline (1012.325 us; speedup 1.0000x reference)
//
#include <hip/hip_runtime.h>
#include <hip/hip_bf16.h>
#include <math.h>

#define NN 50000
#define EE 800000
#define HH 128
#define CHH 64
#define LL 3
#define ZT (NN * HH)
#define SCB 512
#define NBLK 98          // ceil(50001/512)

using bf16 = __hip_bfloat16;
typedef unsigned short u16;
typedef unsigned int u32;
typedef __attribute__((ext_vector_type(8))) short s16x8;
typedef __attribute__((ext_vector_type(4))) float f32x4;

__device__ __forceinline__ float ldbf(const u16* p, size_t i) {
    return __uint_as_float(((u32)p[i]) << 16);
}
__device__ __forceinline__ u16 f2b(float v) {
    bf16 b = __float2bfloat16(v);
    return *reinterpret_cast<u16*>(&b);
}
__device__ __forceinline__ void stbf(u16* p, size_t i, float v) { p[i] = f2b(v); }
__device__ __forceinline__ float blo(u32 w) { return __uint_as_float(w << 16); }
__device__ __forceinline__ float bhi(u32 w) { return __uint_as_float(w & 0xFFFF0000u); }

// ---- zero-fill fallback (diagnostic signature) ----
__global__ __launch_bounds__(256) void zero_out_k(float* __restrict__ out, int n) {
    int i = blockIdx.x * 256 + threadIdx.x;
    if (i < n) out[i] = 0.f;
}

// ---- init: h = bf16(x), flags ----
__global__ __launch_bounds__(256) void init_k(const float* __restrict__ x, u16* __restrict__ h,
        int* __restrict__ deg, int* __restrict__ degns, int* __restrict__ softex,
        int* __restrict__ hardex, int* __restrict__ act) {
    int i = blockIdx.x * 256 + threadIdx.x;
    if (i < ZT) stbf(h, (size_t)i, x[i]);
    if (i < NN) { deg[i] = 1; degns[i] = 0; softex[i] = 0; hardex[i] = 0; }
    if (i < LL) act[i] = 0;
}

// ---- degrees ----
__global__ __launch_bounds__(256) void degree_k(const int* __restrict__ ei,
        int* __restrict__ deg, int* __restrict__ degns) {
    int e = blockIdx.x * 256 + threadIdx.x;
    if (e >= EE) return;
    int s = ei[e], d = ei[EE + e];
    if ((u32)s >= NN || (u32)d >= NN) return;
    atomicAdd(&deg[d], 1);
    if (s != d) atomicAdd(&degns[s], 1);
}

// ---- CSR build ----
__global__ __launch_bounds__(SCB) void scanA_k(const int* __restrict__ deg, int* __restrict__ bsum) {
    int t = threadIdx.x, g = blockIdx.x * SCB + t;
    __shared__ int s[SCB];
    s[t] = (g < NN) ? deg[g] - 1 : 0;
    __syncthreads();
    for (int off = SCB / 2; off > 0; off >>= 1) {
        if (t < off) s[t] += s[t + off];
        __syncthreads();
    }
    if (t == 0) bsum[blockIdx.x] = s[0];
}

__global__ __launch_bounds__(128) void scanB_k(const int* __restrict__ bsum, int* __restrict__ boff) {
    int t = threadIdx.x;
    __shared__ int s[128];
    int v = (t < NBLK) ? bsum[t] : 0;
    s[t] = v;
    __syncthreads();
    for (int off = 1; off < 128; off <<= 1) {
        int x = (t >= off) ? s[t - off] : 0;
        __syncthreads();
        s[t] += x;
        __syncthreads();
    }
    if (t < NBLK) boff[t] = s[t] - v;
}

__global__ __launch_bounds__(SCB) void scanC_k(const int* __restrict__ deg, const int* __restrict__ boff,
        int* __restrict__ rowptr, int* __restrict__ cursor) {
    int t = threadIdx.x, g = blockIdx.x * SCB + t;
    __shared__ int s[SCB];
    int v = (g < NN) ? deg[g] - 1 : 0;
    s[t] = v;
    __syncthreads();
    for (int off = 1; off < SCB; off <<= 1) {
        int x = (t >= off) ? s[t - off] : 0;
        __syncthreads();
        s[t] += x;
        __syncthreads();
    }
    int excl = s[t] - v + boff[blockIdx.x];
    if (g <= NN) rowptr[g] = excl;
    if (g < NN) cursor[g] = excl;
}

__global__ __launch_bounds__(256) void fill_csr_k(const int* __restrict__ ei, const int* __restrict__ deg,
        int* __restrict__ cursor, int* __restrict__ csrc, float* __restrict__ cnrm) {
    int e = blockIdx.x * 256 + threadIdx.x;
    if (e >= EE) return;
    int s = ei[e], d = ei[EE + e];
    if ((u32)s >= NN || (u32)d >= NN) return;
    float nrm = 1.0f / sqrtf((float)deg[s] * (float)deg[d]);
    int pos = atomicAdd(&cursor[d], 1);
    csrc[pos] = s;
    cnrm[pos] = nrm;
}

// ---- pack weights: wt[mat][o][k] = bf16(W[k][o]); mat 0..2 conv, mat 3 = [sw1|hw1] ----
__global__ __launch_bounds__(256) void pack_w_k(const float* __restrict__ w0,
        const float* __restrict__ w1, const float* __restrict__ w2,
        const float* __restrict__ sw1, const float* __restrict__ hw1, u16* __restrict__ wt) {
    int i = blockIdx.x * 256 + threadIdx.x;
    if (i >= 4 * HH * HH) return;
    int mat = i >> 14, rr = i & 16383, o = rr >> 7, k = rr & 127;
    float v;
    if (mat == 0) v = w0[k * HH + o];
    else if (mat == 1) v = w1[k * HH + o];
    else if (mat == 2) v = w2[k * HH + o];
    else v = (o < CHH) ? sw1[k * CHH + o] : hw1[k * CHH + (o - CHH)];
    stbf(wt, (size_t)i, v);
}

// ---- gather + self-loop, pack bf16 hin: hinb[n] = bf16( sum nrm*h[src] + h[n]/deg ) ----
__global__ __launch_bounds__(256) void gather_hin_k(const int* __restrict__ rowptr,
        const int* __restrict__ csrc, const float* __restrict__ cnrm,
        const u16* __restrict__ h, const int* __restrict__ deg, u16* __restrict__ hinb) {
    int node = blockIdx.x * 4 + (threadIdx.x >> 6);
    int lane = threadIdx.x & 63;
    int beg = rowptr[node], end = rowptr[node + 1];
    float a0 = 0.f, a1 = 0.f;
    int e = beg;
    for (; e + 1 < end; e += 2) {
        int s0 = csrc[e], s1 = csrc[e + 1];
        float n0 = cnrm[e], n1 = cnrm[e + 1];
        u32 w0 = *(const u32*)(h + (size_t)s0 * HH + lane * 2);
        u32 w1 = *(const u32*)(h + (size_t)s1 * HH + lane * 2);
        a0 = fmaf(n0, blo(w0), a0); a1 = fmaf(n0, bhi(w0), a1);
        a0 = fmaf(n1, blo(w1), a0); a1 = fmaf(n1, bhi(w1), a1);
    }
    if (e < end) {
        int s0 = csrc[e];
        float n0 = cnrm[e];
        u32 w0 = *(const u32*)(h + (size_t)s0 * HH + lane * 2);
        a0 = fmaf(n0, blo(w0), a0); a1 = fmaf(n0, bhi(w0), a1);
    }
    u32 hw = *(const u32*)(h + (size_t)node * HH + lane * 2);
    float dinv = 1.0f / (float)deg[node];
    a0 = fmaf(blo(hw), dinv, a0);
    a1 = fmaf(bhi(hw), dinv, a1);
    u32 pk = (u32)f2b(a0) | ((u32)f2b(a1) << 16);
    ((u32*)hinb)[(size_t)node * 64 + lane] = pk;
}

// ---- MFMA GEMM: C[n][o] = A[n][:] @ Bt[o][:]  (+bias, +gelu), bf16 in, bf16 out ----
// A layout: row=lane&15, k=(lane>>4)*8+i (b128);  D: col=lane&15, row=(lane>>4)*4+j (m89)
__global__ __launch_bounds__(256) void mfma_gemm_k(const u16* __restrict__ A,
        const u16* __restrict__ Bt, const float* __restrict__ bias, int geluf,
        u16* __restrict__ C) {
    int wave = threadIdx.x >> 6, lane = threadIdx.x & 63;
    int rb = blockIdx.x >> 1, ch = blockIdx.x & 1;
    int row0 = rb * 16;
    int c0 = ch * 64 + wave * 16;
    int r = lane & 15, g = lane >> 4;
    f32x4 acc = {0.f, 0.f, 0.f, 0.f};
    const u16* arow = A + (size_t)(row0 + r) * HH;
    const u16* brow = Bt + (size_t)(c0 + r) * HH;
    #pragma unroll
    for (int kk = 0; kk < 4; ++kk) {
        int k0 = kk * 32 + g * 8;
        s16x8 a = *(const s16x8*)(arow + k0);
        s16x8 b = *(const s16x8*)(brow + k0);
        acc = __builtin_amdgcn_mfma_f32_16x16x32_bf16(a, b, acc, 0, 0, 0);
    }
    int col = c0 + r;
    float bv = bias ? bias[col] : 0.f;
    #pragma unroll
    for (int j = 0; j < 4; ++j) {
        int row = row0 + g * 4 + j;
        float v = acc[j] + bv;
        if (geluf) v = 0.5f * v * (1.0f + erff(v * 0.70710678118654752f));
        stbf(C, (size_t)row * HH + col, v);
    }
}

// ---- soft finish: hid=relu(P[0:64]+sb1); logits via sw2; gumbel compare ----
__global__ __launch_bounds__(256) void soft_fin_k(int li, const u16* __restrict__ P,
        const float* __restrict__ sb1, const float* __restrict__ sw2, const float* __restrict__ sb2,
        const float* __restrict__ gs, int* __restrict__ softex, const int* __restrict__ hardex,
        int* __restrict__ act) {
    int t = threadIdx.x;
    int n = blockIdx.x * 4 + (t >> 6);
    int j = t & 63;
    __shared__ int cnt;
    if (t == 0) cnt = 0;
    __syncthreads();
    float pv = ldbf(P, (size_t)n * HH + j);
    float hid = fmaxf(pv + sb1[j], 0.f);
    float l0 = hid * sw2[j * 2], l1 = hid * sw2[j * 2 + 1];
    #pragma unroll
    for (int off = 32; off > 0; off >>= 1) {
        l0 += __shfl_xor(l0, off);
        l1 += __shfl_xor(l1, off);
    }
    if (j == 0) {
        const float* g = gs + ((size_t)li * NN + n) * 2;
        if (l1 + sb2[1] + g[1] > l0 + sb2[0] + g[0]) softex[n] = 1;
        if (!hardex[n]) atomicAdd(&cnt, 1);   // active counted before this layer's hard exits
    }
    __syncthreads();
    if (t == 0 && cnt) atomicAdd(&act[li], cnt);
}

// ---- readiness scatter ----
__global__ __launch_bounds__(256) void ready_k(const int* __restrict__ ei,
        const int* __restrict__ softex, int* __restrict__ ready) {
    int e = blockIdx.x * 256 + threadIdx.x;
    if (e >= EE) return;
    int s = ei[e], d = ei[EE + e];
    if ((u32)s >= NN || (u32)d >= NN) return;
    if (s != d && softex[d]) atomicAdd(&ready[s], 1);
}

// ---- hard finish: hid=relu(P[64:128]+r*wr+hb1); on exit write z row + exit layer to out ----
__global__ __launch_bounds__(256) void hard_fin_k(int li, const u16* __restrict__ P,
        const u16* __restrict__ h, const float* __restrict__ hw1, const float* __restrict__ hb1,
        const float* __restrict__ hw2, const float* __restrict__ hb2,
        const float* __restrict__ gh, const int* __restrict__ softex,
        int* __restrict__ hardex, const int* __restrict__ ready, const int* __restrict__ degns,
        float* __restrict__ out) {
    int t = threadIdx.x;
    int n = blockIdx.x * 4 + (t >> 6);
    int j = t & 63;
    if (!softex[n] || hardex[n]) return;   // wave-uniform; non-soft-exited never hard-exit (1e6 margin)
    int dns = degns[n]; if (dns < 1) dns = 1;
    float r = (float)ready[n] / (float)dns;
    float pv = ldbf(P, (size_t)n * HH + CHH + j);
    float hid = fmaxf(pv + r * hw1[HH * CHH + j] + hb1[j], 0.f);
    float l0 = hid * hw2[j * 2], l1 = hid * hw2[j * 2 + 1];
    #pragma unroll
    for (int off = 32; off > 0; off >>= 1) {
        l0 += __shfl_xor(l0, off);   // butterfly: all lanes end with identical (commutative) sums
        l1 += __shfl_xor(l1, off);
    }
    const float* g = gh + ((size_t)li * NN + n) * 2;
    if (l1 + hb2[1] + g[1] > l0 + hb2[0] + g[0]) {
        if (j == 0) { hardex[n] = 1; out[ZT + n] = (float)li; }
        u32 hw = *(const u32*)(h + (size_t)n * HH + j * 2);
        out[(size_t)n * HH + j * 2]     = blo(hw);
        out[(size_t)n * HH + j * 2 + 1] = bhi(hw);
    }
}

// ---- tail: non-exited z rows + exit_layers(=LL) + active ----
__global__ __launch_bounds__(256) void tail_k(const u16* __restrict__ h, const int* __restrict__ hardex,
        const int* __restrict__ act, float* __restrict__ out) {
    int i = blockIdx.x * 256 + threadIdx.x;
    if (i < ZT) {
        int n = i >> 7;
        if (!hardex[n]) out[i] = ldbf(h, (size_t)i);
    } else if (i < ZT + NN) {
        if (!hardex[i - ZT]) out[i] = (float)LL;
    } else if (i < ZT + NN + LL) {
        out[i] = (float)act[i - ZT - NN];
    }
}

extern "C" void kernel_launch(void* const* d_in, const int* in_sizes, int n_in,
                              void* d_out, int out_size, void* d_ws, size_t ws_size,
                              hipStream_t stream) {
    float* out = (float*)d_out;                 // output is FLOAT32
    const int OUT_N = ZT + NN + LL;

    static const int CANON[19] = {6400000,1600000,300000,300000,16384,128,16384,128,16384,128,
                                  8192,64,128,2,8256,64,128,2,128};
    static const int SORTED_ROLE[19] = {5,7,9,4,6,8,1,3,2,15,17,14,16,11,13,10,12,18,0};
    int perm[19];
    bool ok = (n_in == 19);
    if (ok) {
        bool mc = true, mr = true, ms = true;
        for (int i = 0; i < 19; ++i) {
            if (in_sizes[i] != CANON[i]) mc = false;
            if (in_sizes[i] != CANON[18 - i]) mr = false;
            if (in_sizes[i] != CANON[SORTED_ROLE[i]]) ms = false;
        }
        if (mc)      for (int c = 0; c < 19; ++c) perm[c] = c;
        else if (mr) for (int c = 0; c < 19; ++c) perm[c] = 18 - c;
        else if (ms) { for (int p = 0; p < 19; ++p) perm[SORTED_ROLE[p]] = p; }
        else         for (int c = 0; c < 19; ++c) perm[c] = c;
    }
    if (!ok) {
        zero_out_k<<<(OUT_N + 255) / 256, 256, 0, stream>>>(out, OUT_N);
        return;
    }

    const float* x  = (const float*)d_in[perm[0]];
    const int*   ei = (const int*)d_in[perm[1]];
    const float* gs = (const float*)d_in[perm[2]];
    const float* gh = (const float*)d_in[perm[3]];
    const float* cw[3] = { (const float*)d_in[perm[4]], (const float*)d_in[perm[6]], (const float*)d_in[perm[8]] };
    const float* cb[3] = { (const float*)d_in[perm[5]], (const float*)d_in[perm[7]], (const float*)d_in[perm[9]] };
    const float* sw1 = (const float*)d_in[perm[10]];
    const float* sb1 = (const float*)d_in[perm[11]];
    const float* sw2 = (const float*)d_in[perm[12]];
    const float* sb2 = (const float*)d_in[perm[13]];
    const float* hw1 = (const float*)d_in[perm[14]];
    const float* hb1 = (const float*)d_in[perm[15]];
    const float* hw2 = (const float*)d_in[perm[16]];
    const float* hb2 = (const float*)d_in[perm[17]];
    // temp_w unused: temp>0 always; softmax monotone -> decisions unaffected

    const size_t H_B    = (size_t)ZT * 2;      // 12.8 MB
    const size_t P_B    = (size_t)ZT * 2;      // hinb / P share this buffer
    const size_t FLAG_B = 200192;
    const size_t ACT_B  = 256;
    const size_t RP_B   = 51200 * 4;
    const size_t BS_B   = 512;
    const size_t CSRC_B = (size_t)EE * 4;
    const size_t CNRM_B = (size_t)EE * 4;
    const size_t WT_B   = 4 * HH * HH * 2;     // 128 KB
    const size_t need = H_B + P_B + 5 * FLAG_B + ACT_B + RP_B + 2 * BS_B + CSRC_B + CNRM_B + WT_B;
    if (ws_size < need) {
        zero_out_k<<<(OUT_N + 255) / 256, 256, 0, stream>>>(out, OUT_N);
        return;
    }

    char* p = (char*)d_ws;
    u16* h    = (u16*)p; p += H_B;
    u16* hinb = (u16*)p; p += P_B;             // also P (heads output) after conv
    int* deg    = (int*)p; p += FLAG_B;
    int* degns  = (int*)p; p += FLAG_B;
    int* ready  = (int*)p; p += FLAG_B;
    int* softex = (int*)p; p += FLAG_B;
    int* hardex = (int*)p; p += FLAG_B;
    int* act    = (int*)p; p += ACT_B;
    int* rowptr = (int*)p; p += RP_B;
    int* bsum   = (int*)p; p += BS_B;
    int* boff   = (int*)p; p += BS_B;
    int* csrc   = (int*)p; p += CSRC_B;
    float* cnrm = (float*)p; p += CNRM_B;
    u16* wt     = (u16*)p; p += WT_B;
    int* cursor = ready;   // alias safe: cursor only in CSR build; ready memset per layer

    init_k<<<(ZT + 255) / 256, 256, 0, stream>>>(x, h, deg, degns, softex, hardex, act);
    degree_k<<<(EE + 255) / 256, 256, 0, stream>>>(ei, deg, degns);
    scanA_k<<<NBLK, SCB, 0, stream>>>(deg, bsum);
    scanB_k<<<1, 128, 0, stream>>>(bsum, boff);
    scanC_k<<<NBLK, SCB, 0, stream>>>(deg, boff, rowptr, cursor);
    fill_csr_k<<<(EE + 255) / 256, 256, 0, stream>>>(ei, deg, cursor, csrc, cnrm);
    pack_w_k<<<(4 * HH * HH + 255) / 256, 256, 0, stream>>>(cw[0], cw[1], cw[2], sw1, hw1, wt);

    for (int li = 0; li < LL; ++li) {
        int geluf = (li < LL - 1) ? 1 : 0;
        gather_hin_k<<<NN / 4, 256, 0, stream>>>(rowptr, csrc, cnrm, h, deg, hinb);
        mfma_gemm_k<<<(NN / 16) * 2, 256, 0, stream>>>(hinb, wt + (size_t)li * HH * HH,
                                                       cb[li], geluf, h);
        mfma_gemm_k<<<(NN / 16) * 2, 256, 0, stream>>>(h, wt + (size_t)3 * HH * HH,
                                                       nullptr, 0, hinb);   // P = h @ [sw1|hw1]
        soft_fin_k<<<NN / 4, 256, 0, stream>>>(li, hinb, sb1, sw2, sb2, gs, softex, hardex, act);
        hipMemsetAsync(ready, 0, (size_t)NN * 4, stream);
        ready_k<<<(EE + 255) / 256, 256, 0, stream>>>(ei, softex, ready);
        hard_fin_k<<<NN / 4, 256, 0, stream>>>(li, hinb, h, hw1, hb1, hw2, hb2, gh, softex,
                                               hardex, ready, degns, out);
    }
    tail_k<<<(OUT_N + 255) / 256, 256, 0, stream>>>(h, hardex, act, out);
}

// Round 10
// 623.324 us; speedup vs baseline: 1.6241x; 1.6241x over previous
//
#include <hip/hip_runtime.h>
#include <hip/hip_bf16.h>
#include <math.h>

#define NN 50000
#define EE 800000
#define HH 128
#define CHH 64
#define LL 3
#define ZT (NN * HH)
#define SCB 512
#define NBLK 98          // ceil(50001/512)

using bf16 = __hip_bfloat16;
typedef unsigned short u16;
typedef unsigned int u32;
typedef __attribute__((ext_vector_type(8))) short s16x8;
typedef __attribute__((ext_vector_type(4))) float f32x4;

__device__ __forceinline__ float ldbf(const u16* p, size_t i) {
    return __uint_as_float(((u32)p[i]) << 16);
}
__device__ __forceinline__ u16 f2b(float v) {
    bf16 b = __float2bfloat16(v);
    return *reinterpret_cast<u16*>(&b);
}
__device__ __forceinline__ void stbf(u16* p, size_t i, float v) { p[i] = f2b(v); }
__device__ __forceinline__ float blo(u32 w) { return __uint_as_float(w << 16); }
__device__ __forceinline__ float bhi(u32 w) { return __uint_as_float(w & 0xFFFF0000u); }

// ---- zero-fill fallback (diagnostic signature) ----
__global__ __launch_bounds__(256) void zero_out_k(float* __restrict__ out, int n) {
    int i = blockIdx.x * 256 + threadIdx.x;
    if (i < n) out[i] = 0.f;
}

// ---- init: h = bf16(x), flags ----
__global__ __launch_bounds__(256) void init_k(const float* __restrict__ x, u16* __restrict__ h,
        int* __restrict__ deg, int* __restrict__ degns, int* __restrict__ softex,
        int* __restrict__ hardex, int* __restrict__ exitl, int* __restrict__ act) {
    int i = blockIdx.x * 256 + threadIdx.x;
    if (i < ZT) stbf(h, (size_t)i, x[i]);
    if (i < NN) { deg[i] = 1; degns[i] = 0; softex[i] = 0; hardex[i] = 0; exitl[i] = LL; }
    if (i < LL) act[i] = 0;
}

// ---- degrees ----
__global__ __launch_bounds__(256) void degree_k(const int* __restrict__ ei,
        int* __restrict__ deg, int* __restrict__ degns) {
    int e = blockIdx.x * 256 + threadIdx.x;
    if (e >= EE) return;
    int s = ei[e], d = ei[EE + e];
    if ((u32)s >= NN || (u32)d >= NN) return;
    atomicAdd(&deg[d], 1);
    if (s != d) atomicAdd(&degns[s], 1);
}

// ---- CSR build ----
__global__ __launch_bounds__(SCB) void scanA_k(const int* __restrict__ deg, int* __restrict__ bsum) {
    int t = threadIdx.x, g = blockIdx.x * SCB + t;
    __shared__ int s[SCB];
    s[t] = (g < NN) ? deg[g] - 1 : 0;
    __syncthreads();
    for (int off = SCB / 2; off > 0; off >>= 1) {
        if (t < off) s[t] += s[t + off];
        __syncthreads();
    }
    if (t == 0) bsum[blockIdx.x] = s[0];
}

__global__ __launch_bounds__(128) void scanB_k(const int* __restrict__ bsum, int* __restrict__ boff) {
    int t = threadIdx.x;
    __shared__ int s[128];
    int v = (t < NBLK) ? bsum[t] : 0;
    s[t] = v;
    __syncthreads();
    for (int off = 1; off < 128; off <<= 1) {
        int x = (t >= off) ? s[t - off] : 0;
        __syncthreads();
        s[t] += x;
        __syncthreads();
    }
    if (t < NBLK) boff[t] = s[t] - v;
}

__global__ __launch_bounds__(SCB) void scanC_k(const int* __restrict__ deg, const int* __restrict__ boff,
        int* __restrict__ rowptr, int* __restrict__ cursor) {
    int t = threadIdx.x, g = blockIdx.x * SCB + t;
    __shared__ int s[SCB];
    int v = (g < NN) ? deg[g] - 1 : 0;
    s[t] = v;
    __syncthreads();
    for (int off = 1; off < SCB; off <<= 1) {
        int x = (t >= off) ? s[t - off] : 0;
        __syncthreads();
        s[t] += x;
        __syncthreads();
    }
    int excl = s[t] - v + boff[blockIdx.x];
    if (g <= NN) rowptr[g] = excl;
    if (g < NN) cursor[g] = excl;
}

__global__ __launch_bounds__(256) void fill_csr_k(const int* __restrict__ ei, const int* __restrict__ deg,
        int* __restrict__ cursor, int* __restrict__ csrc, float* __restrict__ cnrm) {
    int e = blockIdx.x * 256 + threadIdx.x;
    if (e >= EE) return;
    int s = ei[e], d = ei[EE + e];
    if ((u32)s >= NN || (u32)d >= NN) return;
    float nrm = 1.0f / sqrtf((float)deg[s] * (float)deg[d]);
    int pos = atomicAdd(&cursor[d], 1);
    csrc[pos] = s;
    cnrm[pos] = nrm;
}

// ---- pack weights: wt[mat][o][k] = bf16(W[k][o]); mat 0..2 conv, mat 3 = [sw1|hw1] ----
__global__ __launch_bounds__(256) void pack_w_k(const float* __restrict__ w0,
        const float* __restrict__ w1, const float* __restrict__ w2,
        const float* __restrict__ sw1, const float* __restrict__ hw1, u16* __restrict__ wt) {
    int i = blockIdx.x * 256 + threadIdx.x;
    if (i >= 4 * HH * HH) return;
    int mat = i >> 14, rr = i & 16383, o = rr >> 7, k = rr & 127;
    float v;
    if (mat == 0) v = w0[k * HH + o];
    else if (mat == 1) v = w1[k * HH + o];
    else if (mat == 2) v = w2[k * HH + o];
    else v = (o < CHH) ? sw1[k * CHH + o] : hw1[k * CHH + (o - CHH)];
    stbf(wt, (size_t)i, v);
}

// ---- gather + self-loop, pack bf16 hin ----
__global__ __launch_bounds__(256) void gather_hin_k(const int* __restrict__ rowptr,
        const int* __restrict__ csrc, const float* __restrict__ cnrm,
        const u16* __restrict__ h, const int* __restrict__ deg, u16* __restrict__ hinb) {
    int node = blockIdx.x * 4 + (threadIdx.x >> 6);
    int lane = threadIdx.x & 63;
    int beg = rowptr[node], end = rowptr[node + 1];
    float a0 = 0.f, a1 = 0.f;
    int e = beg;
    for (; e + 1 < end; e += 2) {
        int s0 = csrc[e], s1 = csrc[e + 1];
        float n0 = cnrm[e], n1 = cnrm[e + 1];
        u32 w0 = *(const u32*)(h + (size_t)s0 * HH + lane * 2);
        u32 w1 = *(const u32*)(h + (size_t)s1 * HH + lane * 2);
        a0 = fmaf(n0, blo(w0), a0); a1 = fmaf(n0, bhi(w0), a1);
        a0 = fmaf(n1, blo(w1), a0); a1 = fmaf(n1, bhi(w1), a1);
    }
    if (e < end) {
        int s0 = csrc[e];
        float n0 = cnrm[e];
        u32 w0 = *(const u32*)(h + (size_t)s0 * HH + lane * 2);
        a0 = fmaf(n0, blo(w0), a0); a1 = fmaf(n0, bhi(w0), a1);
    }
    u32 hw = *(const u32*)(h + (size_t)node * HH + lane * 2);
    float dinv = 1.0f / (float)deg[node];
    a0 = fmaf(blo(hw), dinv, a0);
    a1 = fmaf(bhi(hw), dinv, a1);
    u32 pk = (u32)f2b(a0) | ((u32)f2b(a1) << 16);
    ((u32*)hinb)[(size_t)node * 64 + lane] = pk;
}

// ---- MFMA GEMM: C[n][o] = A[n][:] @ Bt[o][:] (+bias,+gelu), bf16 in/out ----
__global__ __launch_bounds__(256) void mfma_gemm_k(const u16* __restrict__ A,
        const u16* __restrict__ Bt, const float* __restrict__ bias, int geluf,
        u16* __restrict__ C) {
    int wave = threadIdx.x >> 6, lane = threadIdx.x & 63;
    int rb = blockIdx.x >> 1, ch = blockIdx.x & 1;
    int row0 = rb * 16;
    int c0 = ch * 64 + wave * 16;
    int r = lane & 15, g = lane >> 4;
    f32x4 acc = {0.f, 0.f, 0.f, 0.f};
    const u16* arow = A + (size_t)(row0 + r) * HH;
    const u16* brow = Bt + (size_t)(c0 + r) * HH;
    #pragma unroll
    for (int kk = 0; kk < 4; ++kk) {
        int k0 = kk * 32 + g * 8;
        s16x8 a = *(const s16x8*)(arow + k0);
        s16x8 b = *(const s16x8*)(brow + k0);
        acc = __builtin_amdgcn_mfma_f32_16x16x32_bf16(a, b, acc, 0, 0, 0);
    }
    int col = c0 + r;
    float bv = bias ? bias[col] : 0.f;
    #pragma unroll
    for (int j = 0; j < 4; ++j) {
        int row = row0 + g * 4 + j;
        float v = acc[j] + bv;
        if (geluf) v = 0.5f * v * (1.0f + erff(v * 0.70710678118654752f));
        stbf(C, (size_t)row * HH + col, v);
    }
}

// ---- soft finish: 4 nodes/wave, NO global atomics ----
__global__ __launch_bounds__(256) void soft_fin_k(int li, const u16* __restrict__ P,
        const float* __restrict__ sb1, const float* __restrict__ sw2, const float* __restrict__ sb2,
        const float* __restrict__ gs, int* __restrict__ softex) {
    int wv = blockIdx.x * 4 + (threadIdx.x >> 6);   // 0..12499
    int j = threadIdx.x & 63;
    int n0 = wv * 4;
    float b1 = sb1[j], w20 = sw2[j * 2], w21 = sw2[j * 2 + 1];
    float l0[4], l1[4];
    #pragma unroll
    for (int i = 0; i < 4; ++i) {
        float pv = ldbf(P, (size_t)(n0 + i) * HH + j);
        float hid = fmaxf(pv + b1, 0.f);
        l0[i] = hid * w20;
        l1[i] = hid * w21;
    }
    #pragma unroll
    for (int off = 32; off > 0; off >>= 1) {
        #pragma unroll
        for (int i = 0; i < 4; ++i) {
            l0[i] += __shfl_xor(l0[i], off);
            l1[i] += __shfl_xor(l1[i], off);
        }
    }
    if (j == 0) {
        #pragma unroll
        for (int i = 0; i < 4; ++i) {      // static indexing (rule #20)
            int n = n0 + i;
            const float* g = gs + ((size_t)li * NN + n) * 2;
            if (l1[i] + sb2[1] + g[1] > l0[i] + sb2[0] + g[0]) softex[n] = 1;
        }
    }
}

// ---- readiness scatter ----
__global__ __launch_bounds__(256) void ready_k(const int* __restrict__ ei,
        const int* __restrict__ softex, int* __restrict__ ready) {
    int e = blockIdx.x * 256 + threadIdx.x;
    if (e >= EE) return;
    int s = ei[e], d = ei[EE + e];
    if ((u32)s >= NN || (u32)d >= NN) return;
    if (s != d && softex[d]) atomicAdd(&ready[s], 1);
}

// ---- hard finish: on exit record exitl + write z row ----
__global__ __launch_bounds__(256) void hard_fin_k(int li, const u16* __restrict__ P,
        const u16* __restrict__ h, const float* __restrict__ hw1, const float* __restrict__ hb1,
        const float* __restrict__ hw2, const float* __restrict__ hb2,
        const float* __restrict__ gh, const int* __restrict__ softex,
        int* __restrict__ hardex, int* __restrict__ exitl,
        const int* __restrict__ ready, const int* __restrict__ degns,
        float* __restrict__ out) {
    int t = threadIdx.x;
    int n = blockIdx.x * 4 + (t >> 6);
    int j = t & 63;
    if (!softex[n] || hardex[n]) return;   // wave-uniform; non-soft-exited never hard-exit (1e6 margin)
    int dns = degns[n]; if (dns < 1) dns = 1;
    float r = (float)ready[n] / (float)dns;
    float pv = ldbf(P, (size_t)n * HH + CHH + j);
    float hid = fmaxf(pv + r * hw1[HH * CHH + j] + hb1[j], 0.f);
    float l0 = hid * hw2[j * 2], l1 = hid * hw2[j * 2 + 1];
    #pragma unroll
    for (int off = 32; off > 0; off >>= 1) {
        l0 += __shfl_xor(l0, off);   // butterfly: identical sums on all lanes
        l1 += __shfl_xor(l1, off);
    }
    const float* g = gh + ((size_t)li * NN + n) * 2;
    if (l1 + hb2[1] + g[1] > l0 + hb2[0] + g[0]) {
        if (j == 0) { hardex[n] = 1; exitl[n] = li; }
        u32 hw = *(const u32*)(h + (size_t)n * HH + j * 2);
        out[(size_t)n * HH + j * 2]     = blo(hw);
        out[(size_t)n * HH + j * 2 + 1] = bhi(hw);
    }
}

// ---- tail: non-exited z rows + exit_layers; per-block exit histogram -> act ----
__global__ __launch_bounds__(256) void tail_k(const u16* __restrict__ h, const int* __restrict__ exitl,
        float* __restrict__ out, int* __restrict__ act) {
    __shared__ int c[LL];
    int t = threadIdx.x;
    int i = blockIdx.x * 256 + t;
    if (t < LL) c[t] = 0;
    __syncthreads();
    if (i < ZT) {
        int n = i >> 7;
        if (exitl[n] == LL) out[i] = ldbf(h, (size_t)i);
    } else if (i < ZT + NN) {
        int e = exitl[i - ZT];
        out[i] = (float)e;
        if (e < LL) atomicAdd(&c[e], 1);    // LDS atomic
    }
    __syncthreads();
    if (t < LL && c[t]) atomicAdd(&act[t], c[t]);   // ~196 blocks x 3 global atomics
}

// ---- finalize: active[li] = NN - #{exited before li} ----
__global__ __launch_bounds__(64) void finalize_k(const int* __restrict__ act, float* __restrict__ out) {
    if (threadIdx.x == 0) {
        out[ZT + NN]     = (float)NN;
        out[ZT + NN + 1] = (float)(NN - act[0]);
        out[ZT + NN + 2] = (float)(NN - act[0] - act[1]);
    }
}

extern "C" void kernel_launch(void* const* d_in, const int* in_sizes, int n_in,
                              void* d_out, int out_size, void* d_ws, size_t ws_size,
                              hipStream_t stream) {
    float* out = (float*)d_out;                 // output is FLOAT32
    const int OUT_N = ZT + NN + LL;

    static const int CANON[19] = {6400000,1600000,300000,300000,16384,128,16384,128,16384,128,
                                  8192,64,128,2,8256,64,128,2,128};
    static const int SORTED_ROLE[19] = {5,7,9,4,6,8,1,3,2,15,17,14,16,11,13,10,12,18,0};
    int perm[19];
    bool ok = (n_in == 19);
    if (ok) {
        bool mc = true, mr = true, ms = true;
        for (int i = 0; i < 19; ++i) {
            if (in_sizes[i] != CANON[i]) mc = false;
            if (in_sizes[i] != CANON[18 - i]) mr = false;
            if (in_sizes[i] != CANON[SORTED_ROLE[i]]) ms = false;
        }
        if (mc)      for (int c = 0; c < 19; ++c) perm[c] = c;
        else if (mr) for (int c = 0; c < 19; ++c) perm[c] = 18 - c;
        else if (ms) { for (int p = 0; p < 19; ++p) perm[SORTED_ROLE[p]] = p; }
        else         for (int c = 0; c < 19; ++c) perm[c] = c;
    }
    if (!ok) {
        zero_out_k<<<(OUT_N + 255) / 256, 256, 0, stream>>>(out, OUT_N);
        return;
    }

    const float* x  = (const float*)d_in[perm[0]];
    const int*   ei = (const int*)d_in[perm[1]];
    const float* gs = (const float*)d_in[perm[2]];
    const float* gh = (const float*)d_in[perm[3]];
    const float* cw[3] = { (const float*)d_in[perm[4]], (const float*)d_in[perm[6]], (const float*)d_in[perm[8]] };
    const float* cb[3] = { (const float*)d_in[perm[5]], (const float*)d_in[perm[7]], (const float*)d_in[perm[9]] };
    const float* sw1 = (const float*)d_in[perm[10]];
    const float* sb1 = (const float*)d_in[perm[11]];
    const float* sw2 = (const float*)d_in[perm[12]];
    const float* sb2 = (const float*)d_in[perm[13]];
    const float* hw1 = (const float*)d_in[perm[14]];
    const float* hb1 = (const float*)d_in[perm[15]];
    const float* hw2 = (const float*)d_in[perm[16]];
    const float* hb2 = (const float*)d_in[perm[17]];
    // temp_w unused: temp>0 always; softmax monotone -> decisions unaffected

    const size_t H_B    = (size_t)ZT * 2;
    const size_t P_B    = (size_t)ZT * 2;
    const size_t FLAG_B = 200192;
    const size_t ACT_B  = 256;
    const size_t RP_B   = 51200 * 4;
    const size_t BS_B   = 512;
    const size_t CSRC_B = (size_t)EE * 4;
    const size_t CNRM_B = (size_t)EE * 4;
    const size_t WT_B   = 4 * HH * HH * 2;
    const size_t need = H_B + P_B + 6 * FLAG_B + ACT_B + RP_B + 2 * BS_B + CSRC_B + CNRM_B + WT_B;
    if (ws_size < need) {
        zero_out_k<<<(OUT_N + 255) / 256, 256, 0, stream>>>(out, OUT_N);
        return;
    }

    char* p = (char*)d_ws;
    u16* h    = (u16*)p; p += H_B;
    u16* hinb = (u16*)p; p += P_B;             // also P (heads output)
    int* deg    = (int*)p; p += FLAG_B;
    int* degns  = (int*)p; p += FLAG_B;
    int* ready  = (int*)p; p += FLAG_B;
    int* softex = (int*)p; p += FLAG_B;
    int* hardex = (int*)p; p += FLAG_B;
    int* exitl  = (int*)p; p += FLAG_B;
    int* act    = (int*)p; p += ACT_B;
    int* rowptr = (int*)p; p += RP_B;
    int* bsum   = (int*)p; p += BS_B;
    int* boff   = (int*)p; p += BS_B;
    int* csrc   = (int*)p; p += CSRC_B;
    float* cnrm = (float*)p; p += CNRM_B;
    u16* wt     = (u16*)p; p += WT_B;
    int* cursor = ready;   // alias safe: cursor only in CSR build; ready memset per layer

    init_k<<<(ZT + 255) / 256, 256, 0, stream>>>(x, h, deg, degns, softex, hardex, exitl, act);
    degree_k<<<(EE + 255) / 256, 256, 0, stream>>>(ei, deg, degns);
    scanA_k<<<NBLK, SCB, 0, stream>>>(deg, bsum);
    scanB_k<<<1, 128, 0, stream>>>(bsum, boff);
    scanC_k<<<NBLK, SCB, 0, stream>>>(deg, boff, rowptr, cursor);
    fill_csr_k<<<(EE + 255) / 256, 256, 0, stream>>>(ei, deg, cursor, csrc, cnrm);
    pack_w_k<<<(4 * HH * HH + 255) / 256, 256, 0, stream>>>(cw[0], cw[1], cw[2], sw1, hw1, wt);

    for (int li = 0; li < LL; ++li) {
        int geluf = (li < LL - 1) ? 1 : 0;
        gather_hin_k<<<NN / 4, 256, 0, stream>>>(rowptr, csrc, cnrm, h, deg, hinb);
        mfma_gemm_k<<<(NN / 16) * 2, 256, 0, stream>>>(hinb, wt + (size_t)li * HH * HH,
                                                       cb[li], geluf, h);
        mfma_gemm_k<<<(NN / 16) * 2, 256, 0, stream>>>(h, wt + (size_t)3 * HH * HH,
                                                       nullptr, 0, hinb);   // P = h @ [sw1|hw1]
        soft_fin_k<<<NN / 16, 256, 0, stream>>>(li, hinb, sb1, sw2, sb2, gs, softex);
        hipMemsetAsync(ready, 0, (size_t)NN * 4, stream);
        ready_k<<<(EE + 255) / 256, 256, 0, stream>>>(ei, softex, ready);
        hard_fin_k<<<NN / 4, 256, 0, stream>>>(li, hinb, h, hw1, hb1, hw2, hb2, gh, softex,
                                               hardex, exitl, ready, degns, out);
    }
    tail_k<<<(OUT_N + 255) / 256, 256, 0, stream>>>(h, exitl, out, act);
    finalize_k<<<1, 64, 0, stream>>>(act, out);
}

// Round 11
// 580.883 us; speedup vs baseline: 1.7427x; 1.0731x over previous
//
#include <hip/hip_runtime.h>
#include <hip/hip_bf16.h>
#include <math.h>

#define NN 50000
#define EE 800000
#define HH 128
#define CHH 64
#define LL 3
#define ZT (NN * HH)
#define SCB 512
#define NBLK 98          // ceil(50001/512)

using bf16 = __hip_bfloat16;
typedef unsigned short u16;
typedef unsigned int u32;
typedef __attribute__((ext_vector_type(8))) short s16x8;
typedef __attribute__((ext_vector_type(4))) float f32x4;

__device__ __forceinline__ float ldbf(const u16* p, size_t i) {
    return __uint_as_float(((u32)p[i]) << 16);
}
__device__ __forceinline__ u16 f2b(float v) {
    bf16 b = __float2bfloat16(v);
    return *reinterpret_cast<u16*>(&b);
}
__device__ __forceinline__ void stbf(u16* p, size_t i, float v) { p[i] = f2b(v); }
__device__ __forceinline__ float blo(u32 w) { return __uint_as_float(w << 16); }
__device__ __forceinline__ float bhi(u32 w) { return __uint_as_float(w & 0xFFFF0000u); }

// ---- zero-fill fallback (diagnostic signature) ----
__global__ __launch_bounds__(256) void zero_out_k(float* __restrict__ out, int n) {
    int i = blockIdx.x * 256 + threadIdx.x;
    if (i < n) out[i] = 0.f;
}

// ---- init ----
__global__ __launch_bounds__(256) void init_k(const float* __restrict__ x, u16* __restrict__ h,
        int* __restrict__ deg, int* __restrict__ odeg, int* __restrict__ softex,
        int* __restrict__ hardex, int* __restrict__ exitl, int* __restrict__ act) {
    int i = blockIdx.x * 256 + threadIdx.x;
    if (i < ZT) stbf(h, (size_t)i, x[i]);
    if (i < NN) { deg[i] = 1; odeg[i] = 0; softex[i] = 0; hardex[i] = 0; exitl[i] = LL; }
    if (i < LL) act[i] = 0;
}

// ---- degrees: in-degree (incl self) + non-self out-degree ----
__global__ __launch_bounds__(256) void degree_k(const int* __restrict__ ei,
        int* __restrict__ deg, int* __restrict__ odeg) {
    int e = blockIdx.x * 256 + threadIdx.x;
    if (e >= EE) return;
    int s = ei[e], d = ei[EE + e];
    if ((u32)s >= NN || (u32)d >= NN) return;
    atomicAdd(&deg[d], 1);
    if (s != d) atomicAdd(&odeg[s], 1);
}

// ---- dinv table ----
__global__ __launch_bounds__(256) void dinv_k(const int* __restrict__ deg, float* __restrict__ dinv) {
    int n = blockIdx.x * 256 + threadIdx.x;
    if (n < NN) dinv[n] = 1.0f / sqrtf((float)deg[n]);
}

// ---- generic scans (src[g]-sub) ----
__global__ __launch_bounds__(SCB) void scanA_k(const int* __restrict__ src, int sub, int* __restrict__ bsum) {
    int t = threadIdx.x, g = blockIdx.x * SCB + t;
    __shared__ int s[SCB];
    s[t] = (g < NN) ? src[g] - sub : 0;
    __syncthreads();
    for (int off = SCB / 2; off > 0; off >>= 1) {
        if (t < off) s[t] += s[t + off];
        __syncthreads();
    }
    if (t == 0) bsum[blockIdx.x] = s[0];
}

__global__ __launch_bounds__(128) void scanB_k(const int* __restrict__ bsum, int* __restrict__ boff) {
    int t = threadIdx.x;
    __shared__ int s[128];
    int v = (t < NBLK) ? bsum[t] : 0;
    s[t] = v;
    __syncthreads();
    for (int off = 1; off < 128; off <<= 1) {
        int x = (t >= off) ? s[t - off] : 0;
        __syncthreads();
        s[t] += x;
        __syncthreads();
    }
    if (t < NBLK) boff[t] = s[t] - v;
}

__global__ __launch_bounds__(SCB) void scanC_k(const int* __restrict__ src, int sub,
        const int* __restrict__ boff, int* __restrict__ rowptr, int* __restrict__ cursor) {
    int t = threadIdx.x, g = blockIdx.x * SCB + t;
    __shared__ int s[SCB];
    int v = (g < NN) ? src[g] - sub : 0;
    s[t] = v;
    __syncthreads();
    for (int off = 1; off < SCB; off <<= 1) {
        int x = (t >= off) ? s[t - off] : 0;
        __syncthreads();
        s[t] += x;
        __syncthreads();
    }
    int excl = s[t] - v + boff[blockIdx.x];
    if (g <= NN) rowptr[g] = excl;
    if (g < NN) cursor[g] = excl;
}

// ---- fill both CSRs in one edge pass ----
__global__ __launch_bounds__(256) void fill_both_k(const int* __restrict__ ei,
        int* __restrict__ icur, int* __restrict__ csrc,
        int* __restrict__ ocur, int* __restrict__ ocol) {
    int e = blockIdx.x * 256 + threadIdx.x;
    if (e >= EE) return;
    int s = ei[e], d = ei[EE + e];
    if ((u32)s >= NN || (u32)d >= NN) return;
    int pos = atomicAdd(&icur[d], 1);
    csrc[pos] = s;
    if (s != d) {
        int pos2 = atomicAdd(&ocur[s], 1);
        ocol[pos2] = d;
    }
}

// ---- pack weights: wt[mat][o][k] = bf16(W[k][o]); mats 0..2 conv, 3 = [sw1|hw1] ----
__global__ __launch_bounds__(256) void pack_w_k(const float* __restrict__ w0,
        const float* __restrict__ w1, const float* __restrict__ w2,
        const float* __restrict__ sw1, const float* __restrict__ hw1, u16* __restrict__ wt) {
    int i = blockIdx.x * 256 + threadIdx.x;
    if (i >= 4 * HH * HH) return;
    int mat = i >> 14, rr = i & 16383, o = rr >> 7, k = rr & 127;
    float v;
    if (mat == 0) v = w0[k * HH + o];
    else if (mat == 1) v = w1[k * HH + o];
    else if (mat == 2) v = w2[k * HH + o];
    else v = (o < CHH) ? sw1[k * CHH + o] : hw1[k * CHH + (o - CHH)];
    stbf(wt, (size_t)i, v);
}

// ---- gather + self-loop: hinb[n] = bf16( sum dinv[s]*dinv[n]*h[s] + h[n]*dinv[n]^2 ) ----
__global__ __launch_bounds__(256) void gather_hin_k(const int* __restrict__ rowptr,
        const int* __restrict__ csrc, const float* __restrict__ dinv,
        const u16* __restrict__ h, u16* __restrict__ hinb) {
    int node = blockIdx.x * 4 + (threadIdx.x >> 6);
    int lane = threadIdx.x & 63;
    int beg = rowptr[node], end = rowptr[node + 1];
    float dvd = dinv[node];
    float a0 = 0.f, a1 = 0.f;
    int e = beg;
    for (; e + 1 < end; e += 2) {
        int s0 = csrc[e], s1 = csrc[e + 1];
        float n0 = dinv[s0], n1 = dinv[s1];
        u32 w0 = *(const u32*)(h + (size_t)s0 * HH + lane * 2);
        u32 w1 = *(const u32*)(h + (size_t)s1 * HH + lane * 2);
        a0 = fmaf(n0, blo(w0), a0); a1 = fmaf(n0, bhi(w0), a1);
        a0 = fmaf(n1, blo(w1), a0); a1 = fmaf(n1, bhi(w1), a1);
    }
    if (e < end) {
        int s0 = csrc[e];
        float n0 = dinv[s0];
        u32 w0 = *(const u32*)(h + (size_t)s0 * HH + lane * 2);
        a0 = fmaf(n0, blo(w0), a0); a1 = fmaf(n0, bhi(w0), a1);
    }
    a0 *= dvd; a1 *= dvd;                      // edge norms share dinv[node]
    u32 hw = *(const u32*)(h + (size_t)node * HH + lane * 2);
    float self = dvd * dvd;                    // self-loop norm = dinv^2 (ref gcn_norm)
    a0 = fmaf(blo(hw), self, a0);
    a1 = fmaf(bhi(hw), self, a1);
    u32 pk = (u32)f2b(a0) | ((u32)f2b(a1) << 16);
    ((u32*)hinb)[(size_t)node * 64 + lane] = pk;
}

// ---- fused double MFMA GEMM: h = act(hinb@Wc + b);  P(=hinb) = h@[sw1|hw1] ----
// block: 16 rows, 4 waves; wave w covers cols [w*32, w*32+32)
__global__ __launch_bounds__(256) void fused_gemm_k(u16* __restrict__ hinb,
        const u16* __restrict__ Wc, const u16* __restrict__ Wh,
        const float* __restrict__ bias, int geluf, u16* __restrict__ h) {
    __shared__ u16 hl[16 * HH];                 // swizzled h tile
    int wave = threadIdx.x >> 6, lane = threadIdx.x & 63;
    int row0 = blockIdx.x * 16;
    int r = lane & 15, g = lane >> 4;
    // ---- GEMM1: conv ----
    const u16* arow = hinb + (size_t)(row0 + r) * HH;
    s16x8 af[4];
    #pragma unroll
    for (int kk = 0; kk < 4; ++kk) af[kk] = *(const s16x8*)(arow + kk * 32 + g * 8);
    f32x4 acc[2];
    #pragma unroll
    for (int cc = 0; cc < 2; ++cc) {
        int c0 = wave * 32 + cc * 16;
        const u16* brow = Wc + (size_t)(c0 + r) * HH;
        f32x4 a = {0.f, 0.f, 0.f, 0.f};
        #pragma unroll
        for (int kk = 0; kk < 4; ++kk) {
            s16x8 b = *(const s16x8*)(brow + kk * 32 + g * 8);
            a = __builtin_amdgcn_mfma_f32_16x16x32_bf16(af[kk], b, a, 0, 0, 0);
        }
        acc[cc] = a;
    }
    #pragma unroll
    for (int cc = 0; cc < 2; ++cc) {
        int col = wave * 32 + cc * 16 + r;
        float bv = bias[col];
        #pragma unroll
        for (int j = 0; j < 4; ++j) {
            int row = g * 4 + j;
            float v = acc[cc][j] + bv;
            if (geluf) v = 0.5f * v * (1.0f + erff(v * 0.70710678118654752f));
            stbf(h, (size_t)(row0 + row) * HH + col, v);
            int chunk = (col >> 3) ^ (row & 7);            // XOR swizzle (G4)
            hl[row * HH + chunk * 8 + (col & 7)] = f2b(v);
        }
    }
    __syncthreads();
    // ---- GEMM2: P = h @ [sw1|hw1], A from swizzled LDS ----
    #pragma unroll
    for (int kk = 0; kk < 4; ++kk) {
        int k0 = kk * 32 + g * 8;
        int chunk = (k0 >> 3) ^ (r & 7);
        af[kk] = *(const s16x8*)(hl + r * HH + chunk * 8);
    }
    #pragma unroll
    for (int cc = 0; cc < 2; ++cc) {
        int c0 = wave * 32 + cc * 16;
        const u16* brow = Wh + (size_t)(c0 + r) * HH;
        f32x4 a = {0.f, 0.f, 0.f, 0.f};
        #pragma unroll
        for (int kk = 0; kk < 4; ++kk) {
            s16x8 b = *(const s16x8*)(brow + kk * 32 + g * 8);
            a = __builtin_amdgcn_mfma_f32_16x16x32_bf16(af[kk], b, a, 0, 0, 0);
        }
        acc[cc] = a;
    }
    #pragma unroll
    for (int cc = 0; cc < 2; ++cc) {
        int col = wave * 32 + cc * 16 + r;
        #pragma unroll
        for (int j = 0; j < 4; ++j) {
            int row = g * 4 + j;
            stbf(hinb, (size_t)(row0 + row) * HH + col, acc[cc][j]);  // rows block-exclusive
        }
    }
}

// ---- soft finish: 4 nodes/wave, no global atomics ----
__global__ __launch_bounds__(256) void soft_fin_k(int li, const u16* __restrict__ P,
        const float* __restrict__ sb1, const float* __restrict__ sw2, const float* __restrict__ sb2,
        const float* __restrict__ gs, int* __restrict__ softex) {
    int wv = blockIdx.x * 4 + (threadIdx.x >> 6);
    int j = threadIdx.x & 63;
    int n0 = wv * 4;
    float b1 = sb1[j], w20 = sw2[j * 2], w21 = sw2[j * 2 + 1];
    float l0[4], l1[4];
    #pragma unroll
    for (int i = 0; i < 4; ++i) {
        float pv = ldbf(P, (size_t)(n0 + i) * HH + j);
        float hid = fmaxf(pv + b1, 0.f);
        l0[i] = hid * w20;
        l1[i] = hid * w21;
    }
    #pragma unroll
    for (int off = 32; off > 0; off >>= 1) {
        #pragma unroll
        for (int i = 0; i < 4; ++i) {
            l0[i] += __shfl_xor(l0[i], off);
            l1[i] += __shfl_xor(l1[i], off);
        }
    }
    if (j == 0) {
        #pragma unroll
        for (int i = 0; i < 4; ++i) {
            int n = n0 + i;
            const float* g = gs + ((size_t)li * NN + n) * 2;
            if (l1[i] + sb2[1] + g[1] > l0[i] + sb2[0] + g[0]) softex[n] = 1;
        }
    }
}

// ---- hard finish with fused readiness gather over out-CSR ----
__global__ __launch_bounds__(256) void hard_fin_k(int li, const u16* __restrict__ P,
        const u16* __restrict__ h, const float* __restrict__ hw1, const float* __restrict__ hb1,
        const float* __restrict__ hw2, const float* __restrict__ hb2,
        const float* __restrict__ gh, const int* __restrict__ softex,
        int* __restrict__ hardex, int* __restrict__ exitl,
        const int* __restrict__ orow, const int* __restrict__ ocol,
        float* __restrict__ out) {
    int t = threadIdx.x;
    int n = blockIdx.x * 4 + (t >> 6);
    int j = t & 63;
    if (!softex[n] || hardex[n]) return;   // wave-uniform; non-soft-exited never hard-exit
    int ob = orow[n], oe = orow[n + 1];
    int cnt = 0;
    for (int e = ob + j; e < oe; e += 64) cnt += softex[ocol[e]];
    #pragma unroll
    for (int off = 32; off > 0; off >>= 1) cnt += __shfl_xor(cnt, off);
    int dns = oe - ob; if (dns < 1) dns = 1;
    float r = (float)cnt / (float)dns;
    float pv = ldbf(P, (size_t)n * HH + CHH + j);
    float hid = fmaxf(pv + r * hw1[HH * CHH + j] + hb1[j], 0.f);
    float l0 = hid * hw2[j * 2], l1 = hid * hw2[j * 2 + 1];
    #pragma unroll
    for (int off = 32; off > 0; off >>= 1) {
        l0 += __shfl_xor(l0, off);   // butterfly: identical sums on all lanes
        l1 += __shfl_xor(l1, off);
    }
    const float* g = gh + ((size_t)li * NN + n) * 2;
    if (l1 + hb2[1] + g[1] > l0 + hb2[0] + g[0]) {
        if (j == 0) { hardex[n] = 1; exitl[n] = li; }
        u32 hw = *(const u32*)(h + (size_t)n * HH + j * 2);
        out[(size_t)n * HH + j * 2]     = blo(hw);
        out[(size_t)n * HH + j * 2 + 1] = bhi(hw);
    }
}

// ---- tail: non-exited z rows + exit_layers; per-block exit histogram -> act ----
__global__ __launch_bounds__(256) void tail_k(const u16* __restrict__ h, const int* __restrict__ exitl,
        float* __restrict__ out, int* __restrict__ act) {
    __shared__ int c[LL];
    int t = threadIdx.x;
    int i = blockIdx.x * 256 + t;
    if (t < LL) c[t] = 0;
    __syncthreads();
    if (i < ZT) {
        int n = i >> 7;
        if (exitl[n] == LL) out[i] = ldbf(h, (size_t)i);
    } else if (i < ZT + NN) {
        int e = exitl[i - ZT];
        out[i] = (float)e;
        if (e < LL) atomicAdd(&c[e], 1);
    }
    __syncthreads();
    if (t < LL && c[t]) atomicAdd(&act[t], c[t]);
}

// ---- finalize active counts ----
__global__ __launch_bounds__(64) void finalize_k(const int* __restrict__ act, float* __restrict__ out) {
    if (threadIdx.x == 0) {
        out[ZT + NN]     = (float)NN;
        out[ZT + NN + 1] = (float)(NN - act[0]);
        out[ZT + NN + 2] = (float)(NN - act[0] - act[1]);
    }
}

extern "C" void kernel_launch(void* const* d_in, const int* in_sizes, int n_in,
                              void* d_out, int out_size, void* d_ws, size_t ws_size,
                              hipStream_t stream) {
    float* out = (float*)d_out;                 // output is FLOAT32
    const int OUT_N = ZT + NN + LL;

    static const int CANON[19] = {6400000,1600000,300000,300000,16384,128,16384,128,16384,128,
                                  8192,64,128,2,8256,64,128,2,128};
    static const int SORTED_ROLE[19] = {5,7,9,4,6,8,1,3,2,15,17,14,16,11,13,10,12,18,0};
    int perm[19];
    bool ok = (n_in == 19);
    if (ok) {
        bool mc = true, mr = true, ms = true;
        for (int i = 0; i < 19; ++i) {
            if (in_sizes[i] != CANON[i]) mc = false;
            if (in_sizes[i] != CANON[18 - i]) mr = false;
            if (in_sizes[i] != CANON[SORTED_ROLE[i]]) ms = false;
        }
        if (mc)      for (int c = 0; c < 19; ++c) perm[c] = c;
        else if (mr) for (int c = 0; c < 19; ++c) perm[c] = 18 - c;
        else if (ms) { for (int p = 0; p < 19; ++p) perm[SORTED_ROLE[p]] = p; }
        else         for (int c = 0; c < 19; ++c) perm[c] = c;
    }
    if (!ok) {
        zero_out_k<<<(OUT_N + 255) / 256, 256, 0, stream>>>(out, OUT_N);
        return;
    }

    const float* x  = (const float*)d_in[perm[0]];
    const int*   ei = (const int*)d_in[perm[1]];
    const float* gs = (const float*)d_in[perm[2]];
    const float* gh = (const float*)d_in[perm[3]];
    const float* cw[3] = { (const float*)d_in[perm[4]], (const float*)d_in[perm[6]], (const float*)d_in[perm[8]] };
    const float* cb[3] = { (const float*)d_in[perm[5]], (const float*)d_in[perm[7]], (const float*)d_in[perm[9]] };
    const float* sw1 = (const float*)d_in[perm[10]];
    const float* sb1 = (const float*)d_in[perm[11]];
    const float* sw2 = (const float*)d_in[perm[12]];
    const float* sb2 = (const float*)d_in[perm[13]];
    const float* hw1 = (const float*)d_in[perm[14]];
    const float* hb1 = (const float*)d_in[perm[15]];
    const float* hw2 = (const float*)d_in[perm[16]];
    const float* hb2 = (const float*)d_in[perm[17]];
    // temp_w unused: temp>0 always; softmax monotone -> decisions unaffected

    const size_t H_B    = (size_t)ZT * 2;
    const size_t FLAG_B = 200192;
    const size_t ACT_B  = 256;
    const size_t RP_B   = 51200 * 4;
    const size_t BS_B   = 512;
    const size_t CE_B   = (size_t)EE * 4;
    const size_t WT_B   = 4 * HH * HH * 2;
    const size_t need = 2 * H_B + 8 * FLAG_B + ACT_B + 2 * RP_B + 2 * BS_B + 2 * CE_B + WT_B;
    if (ws_size < need) {
        zero_out_k<<<(OUT_N + 255) / 256, 256, 0, stream>>>(out, OUT_N);
        return;
    }

    char* p = (char*)d_ws;
    u16* h    = (u16*)p; p += H_B;
    u16* hinb = (u16*)p; p += H_B;             // also P (heads output)
    int* deg    = (int*)p; p += FLAG_B;
    int* odeg   = (int*)p; p += FLAG_B;
    int* softex = (int*)p; p += FLAG_B;
    int* hardex = (int*)p; p += FLAG_B;
    int* exitl  = (int*)p; p += FLAG_B;
    int* icur   = (int*)p; p += FLAG_B;
    int* ocur   = (int*)p; p += FLAG_B;
    float* dinv = (float*)p; p += FLAG_B;
    int* act    = (int*)p; p += ACT_B;
    int* irow   = (int*)p; p += RP_B;
    int* orow   = (int*)p; p += RP_B;
    int* bsum   = (int*)p; p += BS_B;
    int* boff   = (int*)p; p += BS_B;
    int* csrc   = (int*)p; p += CE_B;
    int* ocol   = (int*)p; p += CE_B;
    u16* wt     = (u16*)p; p += WT_B;

    init_k<<<(ZT + 255) / 256, 256, 0, stream>>>(x, h, deg, odeg, softex, hardex, exitl, act);
    degree_k<<<(EE + 255) / 256, 256, 0, stream>>>(ei, deg, odeg);
    dinv_k<<<(NN + 255) / 256, 256, 0, stream>>>(deg, dinv);
    scanA_k<<<NBLK, SCB, 0, stream>>>(deg, 1, bsum);
    scanB_k<<<1, 128, 0, stream>>>(bsum, boff);
    scanC_k<<<NBLK, SCB, 0, stream>>>(deg, 1, boff, irow, icur);
    scanA_k<<<NBLK, SCB, 0, stream>>>(odeg, 0, bsum);
    scanB_k<<<1, 128, 0, stream>>>(bsum, boff);
    scanC_k<<<NBLK, SCB, 0, stream>>>(odeg, 0, boff, orow, ocur);
    fill_both_k<<<(EE + 255) / 256, 256, 0, stream>>>(ei, icur, csrc, ocur, ocol);
    pack_w_k<<<(4 * HH * HH + 255) / 256, 256, 0, stream>>>(cw[0], cw[1], cw[2], sw1, hw1, wt);

    for (int li = 0; li < LL; ++li) {
        int geluf = (li < LL - 1) ? 1 : 0;
        gather_hin_k<<<NN / 4, 256, 0, stream>>>(irow, csrc, dinv, h, hinb);
        fused_gemm_k<<<NN / 16, 256, 0, stream>>>(hinb, wt + (size_t)li * HH * HH,
                                                  wt + (size_t)3 * HH * HH, cb[li], geluf, h);
        soft_fin_k<<<NN / 16, 256, 0, stream>>>(li, hinb, sb1, sw2, sb2, gs, softex);
        hard_fin_k<<<NN / 4, 256, 0, stream>>>(li, hinb, h, hw1, hb1, hw2, hb2, gh, softex,
                                               hardex, exitl, orow, ocol, out);
    }
    tail_k<<<(OUT_N + 255) / 256, 256, 0, stream>>>(h, exitl, out, act);
    finalize_k<<<1, 64, 0, stream>>>(act, out);
}

// Round 12
// 502.577 us; speedup vs baseline: 2.0143x; 1.1558x over previous
//
#include <hip/hip_runtime.h>
#include <hip/hip_bf16.h>
#include <math.h>

#define NN 50000
#define EE 800000
#define HH 128
#define CHH 64
#define LL 3
#define ZT (NN * HH)
#define SCB 512
#define NBLK 98          // ceil(50001/512)

using bf16 = __hip_bfloat16;
typedef unsigned short u16;
typedef unsigned int u32;
typedef __attribute__((ext_vector_type(8))) short s16x8;
typedef __attribute__((ext_vector_type(4))) float f32x4;

__device__ __forceinline__ float ldbf(const u16* p, size_t i) {
    return __uint_as_float(((u32)p[i]) << 16);
}
__device__ __forceinline__ u16 f2b(float v) {
    bf16 b = __float2bfloat16(v);
    return *reinterpret_cast<u16*>(&b);
}
__device__ __forceinline__ void stbf(u16* p, size_t i, float v) { p[i] = f2b(v); }
__device__ __forceinline__ float blo(u32 w) { return __uint_as_float(w << 16); }
__device__ __forceinline__ float bhi(u32 w) { return __uint_as_float(w & 0xFFFF0000u); }

// ---- zero-fill fallback (diagnostic signature) ----
__global__ __launch_bounds__(256) void zero_out_k(float* __restrict__ out, int n) {
    int i = blockIdx.x * 256 + threadIdx.x;
    if (i < n) out[i] = 0.f;
}

// ---- init ----
__global__ __launch_bounds__(256) void init_k(const float* __restrict__ x, u16* __restrict__ h,
        int* __restrict__ deg, int* __restrict__ odeg, int* __restrict__ softex,
        int* __restrict__ hardex, int* __restrict__ exitl, int* __restrict__ act) {
    int i = blockIdx.x * 256 + threadIdx.x;
    if (i < ZT) stbf(h, (size_t)i, x[i]);
    if (i < NN) { deg[i] = 1; odeg[i] = 0; softex[i] = 0; hardex[i] = 0; exitl[i] = LL; }
    if (i < LL) act[i] = 0;
}

// ---- degrees: in-degree (incl self) + non-self out-degree ----
__global__ __launch_bounds__(256) void degree_k(const int* __restrict__ ei,
        int* __restrict__ deg, int* __restrict__ odeg) {
    int e = blockIdx.x * 256 + threadIdx.x;
    if (e >= EE) return;
    int s = ei[e], d = ei[EE + e];
    if ((u32)s >= NN || (u32)d >= NN) return;
    atomicAdd(&deg[d], 1);
    if (s != d) atomicAdd(&odeg[s], 1);
}

// ---- dinv table ----
__global__ __launch_bounds__(256) void dinv_k(const int* __restrict__ deg, float* __restrict__ dinv) {
    int n = blockIdx.x * 256 + threadIdx.x;
    if (n < NN) dinv[n] = 1.0f / sqrtf((float)deg[n]);
}

// ---- generic scans (src[g]-sub) ----
__global__ __launch_bounds__(SCB) void scanA_k(const int* __restrict__ src, int sub, int* __restrict__ bsum) {
    int t = threadIdx.x, g = blockIdx.x * SCB + t;
    __shared__ int s[SCB];
    s[t] = (g < NN) ? src[g] - sub : 0;
    __syncthreads();
    for (int off = SCB / 2; off > 0; off >>= 1) {
        if (t < off) s[t] += s[t + off];
        __syncthreads();
    }
    if (t == 0) bsum[blockIdx.x] = s[0];
}

__global__ __launch_bounds__(128) void scanB_k(const int* __restrict__ bsum, int* __restrict__ boff) {
    int t = threadIdx.x;
    __shared__ int s[128];
    int v = (t < NBLK) ? bsum[t] : 0;
    s[t] = v;
    __syncthreads();
    for (int off = 1; off < 128; off <<= 1) {
        int x = (t >= off) ? s[t - off] : 0;
        __syncthreads();
        s[t] += x;
        __syncthreads();
    }
    if (t < NBLK) boff[t] = s[t] - v;
}

__global__ __launch_bounds__(SCB) void scanC_k(const int* __restrict__ src, int sub,
        const int* __restrict__ boff, int* __restrict__ rowptr, int* __restrict__ cursor) {
    int t = threadIdx.x, g = blockIdx.x * SCB + t;
    __shared__ int s[SCB];
    int v = (g < NN) ? src[g] - sub : 0;
    s[t] = v;
    __syncthreads();
    for (int off = 1; off < SCB; off <<= 1) {
        int x = (t >= off) ? s[t - off] : 0;
        __syncthreads();
        s[t] += x;
        __syncthreads();
    }
    int excl = s[t] - v + boff[blockIdx.x];
    if (g <= NN) rowptr[g] = excl;
    if (g < NN) cursor[g] = excl;
}

// ---- fill both CSRs in one edge pass (u16 payloads: node ids < 65536) ----
__global__ __launch_bounds__(256) void fill_both_k(const int* __restrict__ ei,
        int* __restrict__ icur, u16* __restrict__ csrc,
        int* __restrict__ ocur, u16* __restrict__ ocol) {
    int e = blockIdx.x * 256 + threadIdx.x;
    if (e >= EE) return;
    int s = ei[e], d = ei[EE + e];
    if ((u32)s >= NN || (u32)d >= NN) return;
    int pos = atomicAdd(&icur[d], 1);
    csrc[pos] = (u16)s;
    if (s != d) {
        int pos2 = atomicAdd(&ocur[s], 1);
        ocol[pos2] = (u16)d;
    }
}

// ---- pack weights: wt[mat][o][k] = bf16(W[k][o]); mats 0..2 conv, 3 = [sw1|hw1] ----
__global__ __launch_bounds__(256) void pack_w_k(const float* __restrict__ w0,
        const float* __restrict__ w1, const float* __restrict__ w2,
        const float* __restrict__ sw1, const float* __restrict__ hw1, u16* __restrict__ wt) {
    int i = blockIdx.x * 256 + threadIdx.x;
    if (i >= 4 * HH * HH) return;
    int mat = i >> 14, rr = i & 16383, o = rr >> 7, k = rr & 127;
    float v;
    if (mat == 0) v = w0[k * HH + o];
    else if (mat == 1) v = w1[k * HH + o];
    else if (mat == 2) v = w2[k * HH + o];
    else v = (o < CHH) ? sw1[k * CHH + o] : hw1[k * CHH + (o - CHH)];
    stbf(wt, (size_t)i, v);
}

// ---- gather + self-loop, unroll x4: hinb[n] = bf16( dinv[n]*sum dinv[s]*h[s] + h[n]*dinv[n]^2 ) ----
__global__ __launch_bounds__(256) void gather_hin_k(const int* __restrict__ rowptr,
        const u16* __restrict__ csrc, const float* __restrict__ dinv,
        const u16* __restrict__ h, u16* __restrict__ hinb) {
    int node = blockIdx.x * 4 + (threadIdx.x >> 6);
    int lane = threadIdx.x & 63;
    int beg = rowptr[node], end = rowptr[node + 1];
    float dvd = dinv[node];
    float a0 = 0.f, a1 = 0.f;
    int e = beg;
    for (; e + 3 < end; e += 4) {
        int s0 = csrc[e], s1 = csrc[e + 1], s2 = csrc[e + 2], s3 = csrc[e + 3];
        float n0 = dinv[s0], n1 = dinv[s1], n2 = dinv[s2], n3 = dinv[s3];
        u32 w0 = *(const u32*)(h + (size_t)s0 * HH + lane * 2);
        u32 w1 = *(const u32*)(h + (size_t)s1 * HH + lane * 2);
        u32 w2 = *(const u32*)(h + (size_t)s2 * HH + lane * 2);
        u32 w3 = *(const u32*)(h + (size_t)s3 * HH + lane * 2);
        a0 = fmaf(n0, blo(w0), a0); a1 = fmaf(n0, bhi(w0), a1);
        a0 = fmaf(n1, blo(w1), a0); a1 = fmaf(n1, bhi(w1), a1);
        a0 = fmaf(n2, blo(w2), a0); a1 = fmaf(n2, bhi(w2), a1);
        a0 = fmaf(n3, blo(w3), a0); a1 = fmaf(n3, bhi(w3), a1);
    }
    for (; e < end; ++e) {
        int s0 = csrc[e];
        float n0 = dinv[s0];
        u32 w0 = *(const u32*)(h + (size_t)s0 * HH + lane * 2);
        a0 = fmaf(n0, blo(w0), a0); a1 = fmaf(n0, bhi(w0), a1);
    }
    a0 *= dvd; a1 *= dvd;
    u32 hw = *(const u32*)(h + (size_t)node * HH + lane * 2);
    float self = dvd * dvd;                    // self-loop norm (ref gcn_norm)
    a0 = fmaf(blo(hw), self, a0);
    a1 = fmaf(bhi(hw), self, a1);
    u32 pk = (u32)f2b(a0) | ((u32)f2b(a1) << 16);
    ((u32*)hinb)[(size_t)node * 64 + lane] = pk;
}

// ---- fused: h = act(hinb@Wc+b); P = h@[sw1|hw1]; soft head decided in-register ----
// block: 16 rows, 4 waves; wave w covers cols [w*32, w*32+32)
__global__ __launch_bounds__(256) void fused_gemm_k(int li, u16* __restrict__ hinb,
        const u16* __restrict__ Wc, const u16* __restrict__ Wh,
        const float* __restrict__ bias, int geluf, u16* __restrict__ h,
        const float* __restrict__ sb1, const float* __restrict__ sw2, const float* __restrict__ sb2,
        const float* __restrict__ gs, int* __restrict__ softex) {
    __shared__ u16 hl[16 * HH];                 // swizzled h tile
    __shared__ float l0s[2][16], l1s[2][16];
    int wave = threadIdx.x >> 6, lane = threadIdx.x & 63;
    int row0 = blockIdx.x * 16;
    int r = lane & 15, g = lane >> 4;
    // ---- GEMM1: conv ----
    const u16* arow = hinb + (size_t)(row0 + r) * HH;
    s16x8 af[4];
    #pragma unroll
    for (int kk = 0; kk < 4; ++kk) af[kk] = *(const s16x8*)(arow + kk * 32 + g * 8);
    f32x4 acc[2];
    #pragma unroll
    for (int cc = 0; cc < 2; ++cc) {
        int c0 = wave * 32 + cc * 16;
        const u16* brow = Wc + (size_t)(c0 + r) * HH;
        f32x4 a = {0.f, 0.f, 0.f, 0.f};
        #pragma unroll
        for (int kk = 0; kk < 4; ++kk) {
            s16x8 b = *(const s16x8*)(brow + kk * 32 + g * 8);
            a = __builtin_amdgcn_mfma_f32_16x16x32_bf16(af[kk], b, a, 0, 0, 0);
        }
        acc[cc] = a;
    }
    #pragma unroll
    for (int cc = 0; cc < 2; ++cc) {
        int col = wave * 32 + cc * 16 + r;
        float bv = bias[col];
        #pragma unroll
        for (int j = 0; j < 4; ++j) {
            int row = g * 4 + j;
            float v = acc[cc][j] + bv;
            if (geluf) v = 0.5f * v * (1.0f + erff(v * 0.70710678118654752f));
            stbf(h, (size_t)(row0 + row) * HH + col, v);
            int chunk = (col >> 3) ^ (row & 7);            // XOR swizzle (G4)
            hl[row * HH + chunk * 8 + (col & 7)] = f2b(v);
        }
    }
    __syncthreads();
    // ---- GEMM2: P = h @ [sw1|hw1], A from swizzled LDS ----
    #pragma unroll
    for (int kk = 0; kk < 4; ++kk) {
        int k0 = kk * 32 + g * 8;
        int chunk = (k0 >> 3) ^ (r & 7);
        af[kk] = *(const s16x8*)(hl + r * HH + chunk * 8);
    }
    #pragma unroll
    for (int cc = 0; cc < 2; ++cc) {
        int c0 = wave * 32 + cc * 16;
        const u16* brow = Wh + (size_t)(c0 + r) * HH;
        f32x4 a = {0.f, 0.f, 0.f, 0.f};
        #pragma unroll
        for (int kk = 0; kk < 4; ++kk) {
            s16x8 b = *(const s16x8*)(brow + kk * 32 + g * 8);
            a = __builtin_amdgcn_mfma_f32_16x16x32_bf16(af[kk], b, a, 0, 0, 0);
        }
        acc[cc] = a;
    }
    if (wave < 2) {
        // ---- soft half (cols 0..63): in-register hidden + logit partials ----
        float pl0[4] = {0.f, 0.f, 0.f, 0.f}, pl1[4] = {0.f, 0.f, 0.f, 0.f};
        #pragma unroll
        for (int cc = 0; cc < 2; ++cc) {
            int col = wave * 32 + cc * 16 + r;            // 0..63
            float b1 = sb1[col], w20 = sw2[col * 2], w21 = sw2[col * 2 + 1];
            #pragma unroll
            for (int j = 0; j < 4; ++j) {
                float hv = fmaxf(acc[cc][j] + b1, 0.f);
                pl0[j] = fmaf(hv, w20, pl0[j]);
                pl1[j] = fmaf(hv, w21, pl1[j]);
            }
        }
        #pragma unroll
        for (int off = 1; off < 16; off <<= 1) {          // reduce across the 16-lane r-group
            #pragma unroll
            for (int j = 0; j < 4; ++j) {
                pl0[j] += __shfl_xor(pl0[j], off);
                pl1[j] += __shfl_xor(pl1[j], off);
            }
        }
        if (r == 0) {
            #pragma unroll
            for (int j = 0; j < 4; ++j) {
                l0s[wave][g * 4 + j] = pl0[j];
                l1s[wave][g * 4 + j] = pl1[j];
            }
        }
    } else {
        // ---- hard half (cols 64..127): store P to hinb ----
        #pragma unroll
        for (int cc = 0; cc < 2; ++cc) {
            int col = wave * 32 + cc * 16 + r;
            #pragma unroll
            for (int j = 0; j < 4; ++j) {
                int row = g * 4 + j;
                stbf(hinb, (size_t)(row0 + row) * HH + col, acc[cc][j]);  // rows block-exclusive
            }
        }
    }
    __syncthreads();
    if (threadIdx.x < 16) {
        int row = threadIdx.x, n = row0 + row;
        float l0 = l0s[0][row] + l0s[1][row] + sb2[0];
        float l1 = l1s[0][row] + l1s[1][row] + sb2[1];
        const float* gg = gs + ((size_t)li * NN + n) * 2;
        if (l1 + gg[1] > l0 + gg[0]) softex[n] = 1;
    }
}

// ---- hard finish with fused readiness gather over out-CSR ----
__global__ __launch_bounds__(256) void hard_fin_k(int li, const u16* __restrict__ P,
        const u16* __restrict__ h, const float* __restrict__ hw1, const float* __restrict__ hb1,
        const float* __restrict__ hw2, const float* __restrict__ hb2,
        const float* __restrict__ gh, const int* __restrict__ softex,
        int* __restrict__ hardex, int* __restrict__ exitl,
        const int* __restrict__ orow, const u16* __restrict__ ocol,
        float* __restrict__ out) {
    int t = threadIdx.x;
    int n = blockIdx.x * 4 + (t >> 6);
    int j = t & 63;
    if (!softex[n] || hardex[n]) return;   // wave-uniform; non-soft-exited never hard-exit (1e6 margin)
    int ob = orow[n], oe = orow[n + 1];
    int cnt = 0;
    for (int e = ob + j; e < oe; e += 64) cnt += softex[ocol[e]];
    #pragma unroll
    for (int off = 32; off > 0; off >>= 1) cnt += __shfl_xor(cnt, off);
    int dns = oe - ob; if (dns < 1) dns = 1;
    float r = (float)cnt / (float)dns;
    float pv = ldbf(P, (size_t)n * HH + CHH + j);
    float hid = fmaxf(pv + r * hw1[HH * CHH + j] + hb1[j], 0.f);
    float l0 = hid * hw2[j * 2], l1 = hid * hw2[j * 2 + 1];
    #pragma unroll
    for (int off = 32; off > 0; off >>= 1) {
        l0 += __shfl_xor(l0, off);   // butterfly: identical sums on all lanes
        l1 += __shfl_xor(l1, off);
    }
    const float* g = gh + ((size_t)li * NN + n) * 2;
    if (l1 + hb2[1] + g[1] > l0 + hb2[0] + g[0]) {
        if (j == 0) { hardex[n] = 1; exitl[n] = li; }
        u32 hw = *(const u32*)(h + (size_t)n * HH + j * 2);
        out[(size_t)n * HH + j * 2]     = blo(hw);
        out[(size_t)n * HH + j * 2 + 1] = bhi(hw);
    }
}

// ---- tail: non-exited z rows + exit_layers; per-block exit histogram -> act ----
__global__ __launch_bounds__(256) void tail_k(const u16* __restrict__ h, const int* __restrict__ exitl,
        float* __restrict__ out, int* __restrict__ act) {
    __shared__ int c[LL];
    int t = threadIdx.x;
    int i = blockIdx.x * 256 + t;
    if (t < LL) c[t] = 0;
    __syncthreads();
    if (i < ZT) {
        int n = i >> 7;
        if (exitl[n] == LL) out[i] = ldbf(h, (size_t)i);
    } else if (i < ZT + NN) {
        int e = exitl[i - ZT];
        out[i] = (float)e;
        if (e < LL) atomicAdd(&c[e], 1);
    }
    __syncthreads();
    if (t < LL && c[t]) atomicAdd(&act[t], c[t]);
}

// ---- finalize active counts ----
__global__ __launch_bounds__(64) void finalize_k(const int* __restrict__ act, float* __restrict__ out) {
    if (threadIdx.x == 0) {
        out[ZT + NN]     = (float)NN;
        out[ZT + NN + 1] = (float)(NN - act[0]);
        out[ZT + NN + 2] = (float)(NN - act[0] - act[1]);
    }
}

extern "C" void kernel_launch(void* const* d_in, const int* in_sizes, int n_in,
                              void* d_out, int out_size, void* d_ws, size_t ws_size,
                              hipStream_t stream) {
    float* out = (float*)d_out;                 // output is FLOAT32
    const int OUT_N = ZT + NN + LL;

    static const int CANON[19] = {6400000,1600000,300000,300000,16384,128,16384,128,16384,128,
                                  8192,64,128,2,8256,64,128,2,128};
    static const int SORTED_ROLE[19] = {5,7,9,4,6,8,1,3,2,15,17,14,16,11,13,10,12,18,0};
    int perm[19];
    bool ok = (n_in == 19);
    if (ok) {
        bool mc = true, mr = true, ms = true;
        for (int i = 0; i < 19; ++i) {
            if (in_sizes[i] != CANON[i]) mc = false;
            if (in_sizes[i] != CANON[18 - i]) mr = false;
            if (in_sizes[i] != CANON[SORTED_ROLE[i]]) ms = false;
        }
        if (mc)      for (int c = 0; c < 19; ++c) perm[c] = c;
        else if (mr) for (int c = 0; c < 19; ++c) perm[c] = 18 - c;
        else if (ms) { for (int p = 0; p < 19; ++p) perm[SORTED_ROLE[p]] = p; }
        else         for (int c = 0; c < 19; ++c) perm[c] = c;
    }
    if (!ok) {
        zero_out_k<<<(OUT_N + 255) / 256, 256, 0, stream>>>(out, OUT_N);
        return;
    }

    const float* x  = (const float*)d_in[perm[0]];
    const int*   ei = (const int*)d_in[perm[1]];
    const float* gs = (const float*)d_in[perm[2]];
    const float* gh = (const float*)d_in[perm[3]];
    const float* cw[3] = { (const float*)d_in[perm[4]], (const float*)d_in[perm[6]], (const float*)d_in[perm[8]] };
    const float* cb[3] = { (const float*)d_in[perm[5]], (const float*)d_in[perm[7]], (const float*)d_in[perm[9]] };
    const float* sw1 = (const float*)d_in[perm[10]];
    const float* sb1 = (const float*)d_in[perm[11]];
    const float* sw2 = (const float*)d_in[perm[12]];
    const float* sb2 = (const float*)d_in[perm[13]];
    const float* hw1 = (const float*)d_in[perm[14]];
    const float* hb1 = (const float*)d_in[perm[15]];
    const float* hw2 = (const float*)d_in[perm[16]];
    const float* hb2 = (const float*)d_in[perm[17]];
    // temp_w unused: temp>0 always; softmax monotone -> decisions unaffected

    const size_t H_B    = (size_t)ZT * 2;
    const size_t FLAG_B = 200192;
    const size_t ACT_B  = 256;
    const size_t RP_B   = 51200 * 4;
    const size_t BS_B   = 512;
    const size_t CE_B   = (size_t)EE * 2;      // u16 payloads
    const size_t WT_B   = 4 * HH * HH * 2;
    const size_t need = 2 * H_B + 8 * FLAG_B + ACT_B + 2 * RP_B + 2 * BS_B + 2 * CE_B + WT_B;
    if (ws_size < need) {
        zero_out_k<<<(OUT_N + 255) / 256, 256, 0, stream>>>(out, OUT_N);
        return;
    }

    char* p = (char*)d_ws;
    u16* h    = (u16*)p; p += H_B;
    u16* hinb = (u16*)p; p += H_B;             // also P (heads output)
    int* deg    = (int*)p; p += FLAG_B;
    int* odeg   = (int*)p; p += FLAG_B;
    int* softex = (int*)p; p += FLAG_B;
    int* hardex = (int*)p; p += FLAG_B;
    int* exitl  = (int*)p; p += FLAG_B;
    int* icur   = (int*)p; p += FLAG_B;
    int* ocur   = (int*)p; p += FLAG_B;
    float* dinv = (float*)p; p += FLAG_B;
    int* act    = (int*)p; p += ACT_B;
    int* irow   = (int*)p; p += RP_B;
    int* orow   = (int*)p; p += RP_B;
    int* bsum   = (int*)p; p += BS_B;
    int* boff   = (int*)p; p += BS_B;
    u16* csrc   = (u16*)p; p += CE_B;
    u16* ocol   = (u16*)p; p += CE_B;
    u16* wt     = (u16*)p; p += WT_B;

    init_k<<<(ZT + 255) / 256, 256, 0, stream>>>(x, h, deg, odeg, softex, hardex, exitl, act);
    degree_k<<<(EE + 255) / 256, 256, 0, stream>>>(ei, deg, odeg);
    dinv_k<<<(NN + 255) / 256, 256, 0, stream>>>(deg, dinv);
    scanA_k<<<NBLK, SCB, 0, stream>>>(deg, 1, bsum);
    scanB_k<<<1, 128, 0, stream>>>(bsum, boff);
    scanC_k<<<NBLK, SCB, 0, stream>>>(deg, 1, boff, irow, icur);
    scanA_k<<<NBLK, SCB, 0, stream>>>(odeg, 0, bsum);
    scanB_k<<<1, 128, 0, stream>>>(bsum, boff);
    scanC_k<<<NBLK, SCB, 0, stream>>>(odeg, 0, boff, orow, ocur);
    fill_both_k<<<(EE + 255) / 256, 256, 0, stream>>>(ei, icur, csrc, ocur, ocol);
    pack_w_k<<<(4 * HH * HH + 255) / 256, 256, 0, stream>>>(cw[0], cw[1], cw[2], sw1, hw1, wt);

    for (int li = 0; li < LL; ++li) {
        int geluf = (li < LL - 1) ? 1 : 0;
        gather_hin_k<<<NN / 4, 256, 0, stream>>>(irow, csrc, dinv, h, hinb);
        fused_gemm_k<<<NN / 16, 256, 0, stream>>>(li, hinb, wt + (size_t)li * HH * HH,
                                                  wt + (size_t)3 * HH * HH, cb[li], geluf, h,
                                                  sb1, sw2, sb2, gs, softex);
        hard_fin_k<<<NN / 4, 256, 0, stream>>>(li, hinb, h, hw1, hb1, hw2, hb2, gh, softex,
                                               hardex, exitl, orow, ocol, out);
    }
    tail_k<<<(OUT_N + 255) / 256, 256, 0, stream>>>(h, exitl, out, act);
    finalize_k<<<1, 64, 0, stream>>>(act, out);
}

// Round 13
// 415.361 us; speedup vs baseline: 2.4372x; 1.2100x over previous
//
#include <hip/hip_runtime.h>
#include <hip/hip_bf16.h>
#include <math.h>

#define NN 50000
#define EE 800000
#define HH 128
#define CHH 64
#define LL 3
#define ZT (NN * HH)
#define NBK 196          // ceil(50000/256) node buckets
#define EPB 3125         // EE / 256 edges per sort block

using bf16 = __hip_bfloat16;
typedef unsigned short u16;
typedef unsigned int u32;
typedef __attribute__((ext_vector_type(8))) short s16x8;
typedef __attribute__((ext_vector_type(4))) float f32x4;

__device__ __forceinline__ float ldbf(const u16* p, size_t i) {
    return __uint_as_float(((u32)p[i]) << 16);
}
__device__ __forceinline__ u16 f2b(float v) {
    bf16 b = __float2bfloat16(v);
    return *reinterpret_cast<u16*>(&b);
}
__device__ __forceinline__ void stbf(u16* p, size_t i, float v) { p[i] = f2b(v); }
__device__ __forceinline__ float blo(u32 w) { return __uint_as_float(w << 16); }
__device__ __forceinline__ float bhi(u32 w) { return __uint_as_float(w & 0xFFFF0000u); }

// ---- zero-fill fallback (diagnostic signature) ----
__global__ __launch_bounds__(256) void zero_out_k(float* __restrict__ out, int n) {
    int i = blockIdx.x * 256 + threadIdx.x;
    if (i < n) out[i] = 0.f;
}

// ---- init: h=bf16(x), flags ----
__global__ __launch_bounds__(256) void init_k(const float* __restrict__ x, u16* __restrict__ h,
        int* __restrict__ softex, int* __restrict__ hardex, int* __restrict__ exitl,
        int* __restrict__ act) {
    int i = blockIdx.x * 256 + threadIdx.x;
    if (i < ZT) stbf(h, (size_t)i, x[i]);
    if (i < NN) { softex[i] = 0; hardex[i] = 0; exitl[i] = LL; }
    if (i < LL) act[i] = 0;
}

// ---- sort phase 1: per-block bucket histogram (LDS atomics only) ----
__global__ __launch_bounds__(256) void hist_k(const int* __restrict__ ei, int keyoff, int skipself,
        int* __restrict__ hist) {
    __shared__ int hh[NBK];
    int t = threadIdx.x, b = blockIdx.x;
    if (t < NBK) hh[t] = 0;
    __syncthreads();
    int base = b * EPB;
    for (int i = t; i < EPB; i += 256) {
        int e = base + i;
        int s = ei[e], d = ei[EE + e];
        if ((u32)s >= NN || (u32)d >= NN) continue;
        if (skipself && s == d) continue;
        int key = keyoff ? d : s;
        atomicAdd(&hh[key >> 8], 1);
    }
    __syncthreads();
    if (t < NBK) hist[b * NBK + t] = hh[t];
}

// ---- sort phase 2: offsets per (bucket, block) + bucket starts ----
__global__ __launch_bounds__(256) void boffs_k(const int* __restrict__ hist,
        int* __restrict__ boffs, int* __restrict__ bstart) {
    int t = threadIdx.x;
    __shared__ int scn[256];
    int run = 0;
    if (t < NBK) {
        for (int b = 0; b < 256; ++b) {
            boffs[t * 256 + b] = run;
            run += hist[b * NBK + t];
        }
    }
    int v = (t < NBK) ? run : 0;
    scn[t] = v;
    __syncthreads();
    for (int off = 1; off < 256; off <<= 1) {
        int x = (t >= off) ? scn[t - off] : 0;
        __syncthreads();
        scn[t] += x;
        __syncthreads();
    }
    int excl = scn[t] - v;
    if (t < NBK) {
        bstart[t] = excl;
        if (t == NBK - 1) bstart[NBK] = excl + v;
        for (int b = 0; b < 256; ++b) boffs[t * 256 + b] += excl;
    }
}

// ---- sort phase 3: scatter into bucket-contiguous ebuf (LDS cursors, no global atomics) ----
__global__ __launch_bounds__(256) void scat_k(const int* __restrict__ ei, int keyoff, int skipself,
        const int* __restrict__ boffs, u32* __restrict__ ebuf) {
    __shared__ int cur[NBK];
    int t = threadIdx.x, b = blockIdx.x;
    if (t < NBK) cur[t] = boffs[t * 256 + b];
    __syncthreads();
    int base = b * EPB;
    for (int i = t; i < EPB; i += 256) {
        int e = base + i;
        int s = ei[e], d = ei[EE + e];
        if ((u32)s >= NN || (u32)d >= NN) continue;
        if (skipself && s == d) continue;
        int key = keyoff ? d : s;
        int other = keyoff ? s : d;
        int pos = atomicAdd(&cur[key >> 8], 1);
        ebuf[pos] = (u32)other | ((u32)(key & 255) << 16);
    }
}

// ---- sort phase 4: per-bucket fine CSR fill + (optional) deg->dinv ----
__global__ __launch_bounds__(256) void fine_k(const u32* __restrict__ ebuf,
        const int* __restrict__ bstart, int* __restrict__ rowptr, u16* __restrict__ csrx,
        float* __restrict__ dinv, int addself) {
    __shared__ int cnt[256];
    __shared__ int scn[256];
    int t = threadIdx.x, bk = blockIdx.x;
    int eb = bstart[bk], ee = bstart[bk + 1];
    cnt[t] = 0;
    __syncthreads();
    for (int i = eb + t; i < ee; i += 256)
        atomicAdd(&cnt[(ebuf[i] >> 16) & 255], 1);
    __syncthreads();
    int v = cnt[t];
    scn[t] = v;
    __syncthreads();
    for (int off = 1; off < 256; off <<= 1) {
        int x = (t >= off) ? scn[t - off] : 0;
        __syncthreads();
        scn[t] += x;
        __syncthreads();
    }
    int excl = scn[t] - v;
    int n = (bk << 8) + t;
    if (n < NN) {
        rowptr[n] = eb + excl;
        if (dinv) dinv[n] = 1.0f / sqrtf((float)(v + addself));
    }
    if (bk == NBK - 1 && t == 0) rowptr[NN] = ee;
    cnt[t] = excl;   // reuse as cursor
    __syncthreads();
    for (int i = eb + t; i < ee; i += 256) {
        u32 w = ebuf[i];
        int lo = (w >> 16) & 255;
        int pos = atomicAdd(&cnt[lo], 1);
        csrx[eb + pos] = (u16)(w & 0xFFFF);
    }
}

// ---- pack weights: wt[mat][o][k] = bf16(W[k][o]); mats 0..2 conv, 3 = [sw1|hw1] ----
__global__ __launch_bounds__(256) void pack_w_k(const float* __restrict__ w0,
        const float* __restrict__ w1, const float* __restrict__ w2,
        const float* __restrict__ sw1, const float* __restrict__ hw1, u16* __restrict__ wt) {
    int i = blockIdx.x * 256 + threadIdx.x;
    if (i >= 4 * HH * HH) return;
    int mat = i >> 14, rr = i & 16383, o = rr >> 7, k = rr & 127;
    float v;
    if (mat == 0) v = w0[k * HH + o];
    else if (mat == 1) v = w1[k * HH + o];
    else if (mat == 2) v = w2[k * HH + o];
    else v = (o < CHH) ? sw1[k * CHH + o] : hw1[k * CHH + (o - CHH)];
    stbf(wt, (size_t)i, v);
}

// ---- gather + self-loop, unroll x4 ----
__global__ __launch_bounds__(256) void gather_hin_k(const int* __restrict__ rowptr,
        const u16* __restrict__ csrc, const float* __restrict__ dinv,
        const u16* __restrict__ h, u16* __restrict__ hinb) {
    int node = blockIdx.x * 4 + (threadIdx.x >> 6);
    int lane = threadIdx.x & 63;
    int beg = rowptr[node], end = rowptr[node + 1];
    float dvd = dinv[node];
    float a0 = 0.f, a1 = 0.f;
    int e = beg;
    for (; e + 3 < end; e += 4) {
        int s0 = csrc[e], s1 = csrc[e + 1], s2 = csrc[e + 2], s3 = csrc[e + 3];
        float n0 = dinv[s0], n1 = dinv[s1], n2 = dinv[s2], n3 = dinv[s3];
        u32 w0 = *(const u32*)(h + (size_t)s0 * HH + lane * 2);
        u32 w1 = *(const u32*)(h + (size_t)s1 * HH + lane * 2);
        u32 w2 = *(const u32*)(h + (size_t)s2 * HH + lane * 2);
        u32 w3 = *(const u32*)(h + (size_t)s3 * HH + lane * 2);
        a0 = fmaf(n0, blo(w0), a0); a1 = fmaf(n0, bhi(w0), a1);
        a0 = fmaf(n1, blo(w1), a0); a1 = fmaf(n1, bhi(w1), a1);
        a0 = fmaf(n2, blo(w2), a0); a1 = fmaf(n2, bhi(w2), a1);
        a0 = fmaf(n3, blo(w3), a0); a1 = fmaf(n3, bhi(w3), a1);
    }
    for (; e < end; ++e) {
        int s0 = csrc[e];
        float n0 = dinv[s0];
        u32 w0 = *(const u32*)(h + (size_t)s0 * HH + lane * 2);
        a0 = fmaf(n0, blo(w0), a0); a1 = fmaf(n0, bhi(w0), a1);
    }
    a0 *= dvd; a1 *= dvd;
    u32 hw = *(const u32*)(h + (size_t)node * HH + lane * 2);
    float self = dvd * dvd;                    // self-loop norm (ref gcn_norm)
    a0 = fmaf(blo(hw), self, a0);
    a1 = fmaf(bhi(hw), self, a1);
    u32 pk = (u32)f2b(a0) | ((u32)f2b(a1) << 16);
    ((u32*)hinb)[(size_t)node * 64 + lane] = pk;
}

// ---- fused: h = act(hinb@Wc+b); P = h@[sw1|hw1]; soft head decided in-register ----
__global__ __launch_bounds__(256) void fused_gemm_k(int li, u16* __restrict__ hinb,
        const u16* __restrict__ Wc, const u16* __restrict__ Wh,
        const float* __restrict__ bias, int geluf, u16* __restrict__ h,
        const float* __restrict__ sb1, const float* __restrict__ sw2, const float* __restrict__ sb2,
        const float* __restrict__ gs, int* __restrict__ softex) {
    __shared__ u16 hl[16 * HH];                 // swizzled h tile
    __shared__ float l0s[2][16], l1s[2][16];
    int wave = threadIdx.x >> 6, lane = threadIdx.x & 63;
    int row0 = blockIdx.x * 16;
    int r = lane & 15, g = lane >> 4;
    const u16* arow = hinb + (size_t)(row0 + r) * HH;
    s16x8 af[4];
    #pragma unroll
    for (int kk = 0; kk < 4; ++kk) af[kk] = *(const s16x8*)(arow + kk * 32 + g * 8);
    f32x4 acc[2];
    #pragma unroll
    for (int cc = 0; cc < 2; ++cc) {
        int c0 = wave * 32 + cc * 16;
        const u16* brow = Wc + (size_t)(c0 + r) * HH;
        f32x4 a = {0.f, 0.f, 0.f, 0.f};
        #pragma unroll
        for (int kk = 0; kk < 4; ++kk) {
            s16x8 b = *(const s16x8*)(brow + kk * 32 + g * 8);
            a = __builtin_amdgcn_mfma_f32_16x16x32_bf16(af[kk], b, a, 0, 0, 0);
        }
        acc[cc] = a;
    }
    #pragma unroll
    for (int cc = 0; cc < 2; ++cc) {
        int col = wave * 32 + cc * 16 + r;
        float bv = bias[col];
        #pragma unroll
        for (int j = 0; j < 4; ++j) {
            int row = g * 4 + j;
            float v = acc[cc][j] + bv;
            if (geluf) v = 0.5f * v * (1.0f + erff(v * 0.70710678118654752f));
            stbf(h, (size_t)(row0 + row) * HH + col, v);
            int chunk = (col >> 3) ^ (row & 7);            // XOR swizzle (G4)
            hl[row * HH + chunk * 8 + (col & 7)] = f2b(v);
        }
    }
    __syncthreads();
    #pragma unroll
    for (int kk = 0; kk < 4; ++kk) {
        int k0 = kk * 32 + g * 8;
        int chunk = (k0 >> 3) ^ (r & 7);
        af[kk] = *(const s16x8*)(hl + r * HH + chunk * 8);
    }
    #pragma unroll
    for (int cc = 0; cc < 2; ++cc) {
        int c0 = wave * 32 + cc * 16;
        const u16* brow = Wh + (size_t)(c0 + r) * HH;
        f32x4 a = {0.f, 0.f, 0.f, 0.f};
        #pragma unroll
        for (int kk = 0; kk < 4; ++kk) {
            s16x8 b = *(const s16x8*)(brow + kk * 32 + g * 8);
            a = __builtin_amdgcn_mfma_f32_16x16x32_bf16(af[kk], b, a, 0, 0, 0);
        }
        acc[cc] = a;
    }
    if (wave < 2) {
        float pl0[4] = {0.f, 0.f, 0.f, 0.f}, pl1[4] = {0.f, 0.f, 0.f, 0.f};
        #pragma unroll
        for (int cc = 0; cc < 2; ++cc) {
            int col = wave * 32 + cc * 16 + r;            // 0..63
            float b1 = sb1[col], w20 = sw2[col * 2], w21 = sw2[col * 2 + 1];
            #pragma unroll
            for (int j = 0; j < 4; ++j) {
                float hv = fmaxf(acc[cc][j] + b1, 0.f);
                pl0[j] = fmaf(hv, w20, pl0[j]);
                pl1[j] = fmaf(hv, w21, pl1[j]);
            }
        }
        #pragma unroll
        for (int off = 1; off < 16; off <<= 1) {
            #pragma unroll
            for (int j = 0; j < 4; ++j) {
                pl0[j] += __shfl_xor(pl0[j], off);
                pl1[j] += __shfl_xor(pl1[j], off);
            }
        }
        if (r == 0) {
            #pragma unroll
            for (int j = 0; j < 4; ++j) {
                l0s[wave][g * 4 + j] = pl0[j];
                l1s[wave][g * 4 + j] = pl1[j];
            }
        }
    } else {
        #pragma unroll
        for (int cc = 0; cc < 2; ++cc) {
            int col = wave * 32 + cc * 16 + r;
            #pragma unroll
            for (int j = 0; j < 4; ++j) {
                int row = g * 4 + j;
                stbf(hinb, (size_t)(row0 + row) * HH + col, acc[cc][j]);  // rows block-exclusive
            }
        }
    }
    __syncthreads();
    if (threadIdx.x < 16) {
        int row = threadIdx.x, n = row0 + row;
        float l0 = l0s[0][row] + l0s[1][row] + sb2[0];
        float l1 = l1s[0][row] + l1s[1][row] + sb2[1];
        const float* gg = gs + ((size_t)li * NN + n) * 2;
        if (l1 + gg[1] > l0 + gg[0]) softex[n] = 1;
    }
}

// ---- hard finish with fused readiness gather over out-CSR ----
__global__ __launch_bounds__(256) void hard_fin_k(int li, const u16* __restrict__ P,
        const u16* __restrict__ h, const float* __restrict__ hw1, const float* __restrict__ hb1,
        const float* __restrict__ hw2, const float* __restrict__ hb2,
        const float* __restrict__ gh, const int* __restrict__ softex,
        int* __restrict__ hardex, int* __restrict__ exitl,
        const int* __restrict__ orow, const u16* __restrict__ ocol,
        float* __restrict__ out) {
    int t = threadIdx.x;
    int n = blockIdx.x * 4 + (t >> 6);
    int j = t & 63;
    if (!softex[n] || hardex[n]) return;   // wave-uniform; non-soft-exited never hard-exit (1e6 margin)
    int ob = orow[n], oe = orow[n + 1];
    int cnt = 0;
    for (int e = ob + j; e < oe; e += 64) cnt += softex[ocol[e]];
    #pragma unroll
    for (int off = 32; off > 0; off >>= 1) cnt += __shfl_xor(cnt, off);
    int dns = oe - ob; if (dns < 1) dns = 1;
    float r = (float)cnt / (float)dns;
    float pv = ldbf(P, (size_t)n * HH + CHH + j);
    float hid = fmaxf(pv + r * hw1[HH * CHH + j] + hb1[j], 0.f);
    float l0 = hid * hw2[j * 2], l1 = hid * hw2[j * 2 + 1];
    #pragma unroll
    for (int off = 32; off > 0; off >>= 1) {
        l0 += __shfl_xor(l0, off);   // butterfly: identical sums on all lanes
        l1 += __shfl_xor(l1, off);
    }
    const float* g = gh + ((size_t)li * NN + n) * 2;
    if (l1 + hb2[1] + g[1] > l0 + hb2[0] + g[0]) {
        if (j == 0) { hardex[n] = 1; exitl[n] = li; }
        u32 hw = *(const u32*)(h + (size_t)n * HH + j * 2);
        out[(size_t)n * HH + j * 2]     = blo(hw);
        out[(size_t)n * HH + j * 2 + 1] = bhi(hw);
    }
}

// ---- tail: non-exited z rows + exit_layers; per-block exit histogram -> act ----
__global__ __launch_bounds__(256) void tail_k(const u16* __restrict__ h, const int* __restrict__ exitl,
        float* __restrict__ out, int* __restrict__ act) {
    __shared__ int c[LL];
    int t = threadIdx.x;
    int i = blockIdx.x * 256 + t;
    if (t < LL) c[t] = 0;
    __syncthreads();
    if (i < ZT) {
        int n = i >> 7;
        if (exitl[n] == LL) out[i] = ldbf(h, (size_t)i);
    } else if (i < ZT + NN) {
        int e = exitl[i - ZT];
        out[i] = (float)e;
        if (e < LL) atomicAdd(&c[e], 1);
    }
    __syncthreads();
    if (t < LL && c[t]) atomicAdd(&act[t], c[t]);
}

// ---- finalize active counts ----
__global__ __launch_bounds__(64) void finalize_k(const int* __restrict__ act, float* __restrict__ out) {
    if (threadIdx.x == 0) {
        out[ZT + NN]     = (float)NN;
        out[ZT + NN + 1] = (float)(NN - act[0]);
        out[ZT + NN + 2] = (float)(NN - act[0] - act[1]);
    }
}

extern "C" void kernel_launch(void* const* d_in, const int* in_sizes, int n_in,
                              void* d_out, int out_size, void* d_ws, size_t ws_size,
                              hipStream_t stream) {
    float* out = (float*)d_out;                 // output is FLOAT32
    const int OUT_N = ZT + NN + LL;

    static const int CANON[19] = {6400000,1600000,300000,300000,16384,128,16384,128,16384,128,
                                  8192,64,128,2,8256,64,128,2,128};
    static const int SORTED_ROLE[19] = {5,7,9,4,6,8,1,3,2,15,17,14,16,11,13,10,12,18,0};
    int perm[19];
    bool ok = (n_in == 19);
    if (ok) {
        bool mc = true, mr = true, ms = true;
        for (int i = 0; i < 19; ++i) {
            if (in_sizes[i] != CANON[i]) mc = false;
            if (in_sizes[i] != CANON[18 - i]) mr = false;
            if (in_sizes[i] != CANON[SORTED_ROLE[i]]) ms = false;
        }
        if (mc)      for (int c = 0; c < 19; ++c) perm[c] = c;
        else if (mr) for (int c = 0; c < 19; ++c) perm[c] = 18 - c;
        else if (ms) { for (int p = 0; p < 19; ++p) perm[SORTED_ROLE[p]] = p; }
        else         for (int c = 0; c < 19; ++c) perm[c] = c;
    }
    if (!ok) {
        zero_out_k<<<(OUT_N + 255) / 256, 256, 0, stream>>>(out, OUT_N);
        return;
    }

    const float* x  = (const float*)d_in[perm[0]];
    const int*   ei = (const int*)d_in[perm[1]];
    const float* gs = (const float*)d_in[perm[2]];
    const float* gh = (const float*)d_in[perm[3]];
    const float* cw[3] = { (const float*)d_in[perm[4]], (const float*)d_in[perm[6]], (const float*)d_in[perm[8]] };
    const float* cb[3] = { (const float*)d_in[perm[5]], (const float*)d_in[perm[7]], (const float*)d_in[perm[9]] };
    const float* sw1 = (const float*)d_in[perm[10]];
    const float* sb1 = (const float*)d_in[perm[11]];
    const float* sw2 = (const float*)d_in[perm[12]];
    const float* sb2 = (const float*)d_in[perm[13]];
    const float* hw1 = (const float*)d_in[perm[14]];
    const float* hb1 = (const float*)d_in[perm[15]];
    const float* hw2 = (const float*)d_in[perm[16]];
    const float* hb2 = (const float*)d_in[perm[17]];
    // temp_w unused: temp>0 always; softmax monotone -> decisions unaffected

    const size_t H_B    = (size_t)ZT * 2;      // 12.8 MB
    const size_t FLAG_B = 200192;
    const size_t ACT_B  = 256;
    const size_t RP_B   = 200704;              // 50001 ints padded
    const size_t CE_B   = (size_t)EE * 2;      // u16 CSR payloads
    const size_t WT_B   = 4 * HH * HH * 2;
    const size_t need = 2 * H_B + 4 * FLAG_B + ACT_B + 2 * RP_B + 2 * CE_B + WT_B;  // ~30.1 MB
    if (ws_size < need) {
        zero_out_k<<<(OUT_N + 255) / 256, 256, 0, stream>>>(out, OUT_N);
        return;
    }

    char* p = (char*)d_ws;
    u16* h    = (u16*)p; p += H_B;
    u16* hinb = (u16*)p; p += H_B;             // also P; sort scratch lives here pre-layers
    int* softex = (int*)p; p += FLAG_B;
    int* hardex = (int*)p; p += FLAG_B;
    int* exitl  = (int*)p; p += FLAG_B;
    float* dinv = (float*)p; p += FLAG_B;
    int* act    = (int*)p; p += ACT_B;
    int* irow   = (int*)p; p += RP_B;
    int* orow   = (int*)p; p += RP_B;
    u16* csrc   = (u16*)p; p += CE_B;
    u16* ocol   = (u16*)p; p += CE_B;
    u16* wt     = (u16*)p; p += WT_B;

    // sort scratch aliased into hinb (dead until first gather overwrites it)
    char* q = (char*)hinb;
    u32* ebuf  = (u32*)q;  q += (size_t)EE * 4;            // 3.2 MB
    int* hist  = (int*)q;  q += 256 * NBK * 4;             // 200,704
    int* boffs = (int*)q;  q += NBK * 256 * 4;             // 200,704
    int* bstart = (int*)q; q += 1024;                      // NBK+1 ints

    init_k<<<(ZT + 255) / 256, 256, 0, stream>>>(x, h, softex, hardex, exitl, act);

    // in-CSR (key = dst, keep self edges) + deg -> dinv
    hist_k<<<256, 256, 0, stream>>>(ei, 1, 0, hist);
    boffs_k<<<1, 256, 0, stream>>>(hist, boffs, bstart);
    scat_k<<<256, 256, 0, stream>>>(ei, 1, 0, boffs, ebuf);
    fine_k<<<NBK, 256, 0, stream>>>(ebuf, bstart, irow, csrc, dinv, 1);
    // out-CSR (key = src, skip self edges)
    hist_k<<<256, 256, 0, stream>>>(ei, 0, 1, hist);
    boffs_k<<<1, 256, 0, stream>>>(hist, boffs, bstart);
    scat_k<<<256, 256, 0, stream>>>(ei, 0, 1, boffs, ebuf);
    fine_k<<<NBK, 256, 0, stream>>>(ebuf, bstart, orow, ocol, nullptr, 0);

    pack_w_k<<<(4 * HH * HH + 255) / 256, 256, 0, stream>>>(cw[0], cw[1], cw[2], sw1, hw1, wt);

    for (int li = 0; li < LL; ++li) {
        int geluf = (li < LL - 1) ? 1 : 0;
        gather_hin_k<<<NN / 4, 256, 0, stream>>>(irow, csrc, dinv, h, hinb);
        fused_gemm_k<<<NN / 16, 256, 0, stream>>>(li, hinb, wt + (size_t)li * HH * HH,
                                                  wt + (size_t)3 * HH * HH, cb[li], geluf, h,
                                                  sb1, sw2, sb2, gs, softex);
        hard_fin_k<<<NN / 4, 256, 0, stream>>>(li, hinb, h, hw1, hb1, hw2, hb2, gh, softex,
                                               hardex, exitl, orow, ocol, out);
    }
    tail_k<<<(OUT_N + 255) / 256, 256, 0, stream>>>(h, exitl, out, act);
    finalize_k<<<1, 64, 0, stream>>>(act, out);
}

// Round 14
// 366.188 us; speedup vs baseline: 2.7645x; 1.1343x over previous
//
#include <hip/hip_runtime.h>
#include <hip/hip_bf16.h>
#include <math.h>

#define NN 50000
#define EE 800000
#define HH 128
#define CHH 64
#define LL 3
#define ZT (NN * HH)
#define NBK 196          // ceil(50000/256) node buckets
#define EPB 3125         // EE / 256 edges per sort block

using bf16 = __hip_bfloat16;
typedef unsigned short u16;
typedef unsigned int u32;
typedef __attribute__((ext_vector_type(8))) short s16x8;
typedef __attribute__((ext_vector_type(4))) float f32x4;

__device__ __forceinline__ float ldbf(const u16* p, size_t i) {
    return __uint_as_float(((u32)p[i]) << 16);
}
__device__ __forceinline__ u16 f2b(float v) {
    bf16 b = __float2bfloat16(v);
    return *reinterpret_cast<u16*>(&b);
}
__device__ __forceinline__ void stbf(u16* p, size_t i, float v) { p[i] = f2b(v); }
__device__ __forceinline__ float blo(u32 w) { return __uint_as_float(w << 16); }
__device__ __forceinline__ float bhi(u32 w) { return __uint_as_float(w & 0xFFFF0000u); }

// ---- zero-fill fallback (diagnostic signature) ----
__global__ __launch_bounds__(256) void zero_out_k(float* __restrict__ out, int n) {
    int i = blockIdx.x * 256 + threadIdx.x;
    if (i < n) out[i] = 0.f;
}

// ---- init: h=bf16(x), flags ----
__global__ __launch_bounds__(256) void init_k(const float* __restrict__ x, u16* __restrict__ h,
        int* __restrict__ softex, int* __restrict__ hardex, int* __restrict__ exitl,
        int* __restrict__ act) {
    int i = blockIdx.x * 256 + threadIdx.x;
    if (i < ZT) stbf(h, (size_t)i, x[i]);
    if (i < NN) { softex[i] = 0; hardex[i] = 0; exitl[i] = LL; }
    if (i < LL) act[i] = 0;
}

// ---- sort phase 1: both bucket histograms in one edge pass ----
__global__ __launch_bounds__(256) void hist_both_k(const int* __restrict__ ei,
        int* __restrict__ hist1, int* __restrict__ hist2) {
    __shared__ int h1[NBK], h2[NBK];
    int t = threadIdx.x, b = blockIdx.x;
    if (t < NBK) { h1[t] = 0; h2[t] = 0; }
    __syncthreads();
    int base = b * EPB;
    for (int i = t; i < EPB; i += 256) {
        int e = base + i;
        int s = ei[e], d = ei[EE + e];
        if ((u32)s >= NN || (u32)d >= NN) continue;
        atomicAdd(&h1[d >> 8], 1);                 // in-CSR: key=dst, keep self
        if (s != d) atomicAdd(&h2[s >> 8], 1);     // out-CSR: key=src, skip self
    }
    __syncthreads();
    if (t < NBK) { hist1[b * NBK + t] = h1[t]; hist2[b * NBK + t] = h2[t]; }
}

// ---- sort phase 2: offsets per (bucket, block) + bucket starts ----
__global__ __launch_bounds__(256) void boffs_k(const int* __restrict__ hist,
        int* __restrict__ boffs, int* __restrict__ bstart) {
    int t = threadIdx.x;
    __shared__ int scn[256];
    int run = 0;
    if (t < NBK) {
        for (int b = 0; b < 256; ++b) {
            boffs[t * 256 + b] = run;
            run += hist[b * NBK + t];
        }
    }
    int v = (t < NBK) ? run : 0;
    scn[t] = v;
    __syncthreads();
    for (int off = 1; off < 256; off <<= 1) {
        int x = (t >= off) ? scn[t - off] : 0;
        __syncthreads();
        scn[t] += x;
        __syncthreads();
    }
    int excl = scn[t] - v;
    if (t < NBK) {
        bstart[t] = excl;
        if (t == NBK - 1) bstart[NBK] = excl + v;
        for (int b = 0; b < 256; ++b) boffs[t * 256 + b] += excl;
    }
}

// ---- sort phase 3: scatter both ebufs in one edge pass (LDS cursors) ----
__global__ __launch_bounds__(256) void scat_both_k(const int* __restrict__ ei,
        const int* __restrict__ boffs1, u32* __restrict__ ebuf1,
        const int* __restrict__ boffs2, u32* __restrict__ ebuf2) {
    __shared__ int c1[NBK], c2[NBK];
    int t = threadIdx.x, b = blockIdx.x;
    if (t < NBK) { c1[t] = boffs1[t * 256 + b]; c2[t] = boffs2[t * 256 + b]; }
    __syncthreads();
    int base = b * EPB;
    for (int i = t; i < EPB; i += 256) {
        int e = base + i;
        int s = ei[e], d = ei[EE + e];
        if ((u32)s >= NN || (u32)d >= NN) continue;
        int pos = atomicAdd(&c1[d >> 8], 1);
        ebuf1[pos] = (u32)s | ((u32)(d & 255) << 16);
        if (s != d) {
            int pos2 = atomicAdd(&c2[s >> 8], 1);
            ebuf2[pos2] = (u32)d | ((u32)(s & 255) << 16);
        }
    }
}

// ---- sort phase 4 body: per-bucket fine CSR fill (+ optional dinv) ----
__device__ __forceinline__ void fine_body(int bk, const u32* __restrict__ ebuf,
        const int* __restrict__ bstart, int* __restrict__ rowptr, u16* __restrict__ csrx,
        float* __restrict__ dinv, int addself) {
    __shared__ int cnt[256];
    __shared__ int scn[256];
    int t = threadIdx.x;
    int eb = bstart[bk], ee = bstart[bk + 1];
    cnt[t] = 0;
    __syncthreads();
    for (int i = eb + t; i < ee; i += 256)
        atomicAdd(&cnt[(ebuf[i] >> 16) & 255], 1);
    __syncthreads();
    int v = cnt[t];
    scn[t] = v;
    __syncthreads();
    for (int off = 1; off < 256; off <<= 1) {
        int x = (t >= off) ? scn[t - off] : 0;
        __syncthreads();
        scn[t] += x;
        __syncthreads();
    }
    int excl = scn[t] - v;
    int n = (bk << 8) + t;
    if (n < NN) {
        rowptr[n] = eb + excl;
        if (dinv) dinv[n] = 1.0f / sqrtf((float)(v + addself));
    }
    if (bk == NBK - 1 && t == 0) rowptr[NN] = ee;
    __syncthreads();
    cnt[t] = excl;   // reuse as cursor
    __syncthreads();
    for (int i = eb + t; i < ee; i += 256) {
        u32 w = ebuf[i];
        int lo = (w >> 16) & 255;
        int pos = atomicAdd(&cnt[lo], 1);
        csrx[eb + pos] = (u16)(w & 0xFFFF);
    }
}

__global__ __launch_bounds__(256) void fine2_k(const u32* __restrict__ ebuf1,
        const int* __restrict__ bstart1, int* __restrict__ irow, u16* __restrict__ csrc,
        float* __restrict__ dinv, const u32* __restrict__ ebuf2,
        const int* __restrict__ bstart2, int* __restrict__ orow, u16* __restrict__ ocol) {
    if (blockIdx.x < NBK) fine_body(blockIdx.x, ebuf1, bstart1, irow, csrc, dinv, 1);
    else                  fine_body(blockIdx.x - NBK, ebuf2, bstart2, orow, ocol, nullptr, 0);
}

// ---- pack weights: wt[mat][o][k] = bf16(W[k][o]); mats 0..2 conv, 3 = [sw1|hw1] ----
__global__ __launch_bounds__(256) void pack_w_k(const float* __restrict__ w0,
        const float* __restrict__ w1, const float* __restrict__ w2,
        const float* __restrict__ sw1, const float* __restrict__ hw1, u16* __restrict__ wt) {
    int i = blockIdx.x * 256 + threadIdx.x;
    if (i >= 4 * HH * HH) return;
    int mat = i >> 14, rr = i & 16383, o = rr >> 7, k = rr & 127;
    float v;
    if (mat == 0) v = w0[k * HH + o];
    else if (mat == 1) v = w1[k * HH + o];
    else if (mat == 2) v = w2[k * HH + o];
    else v = (o < CHH) ? sw1[k * CHH + o] : hw1[k * CHH + (o - CHH)];
    stbf(wt, (size_t)i, v);
}

// ---- MEGA: gather(h_in)->LDS; h_out = act(hin@Wc+b); P=h@[sw1|hw1]; soft decision ----
// block: 16 rows, 4 waves; P-hard half stored f32 into out z-region (rows not yet exited)
__global__ __launch_bounds__(256) void mega_k(int li, int geluf,
        const int* __restrict__ irow, const u16* __restrict__ csrc, const float* __restrict__ dinv,
        const u16* __restrict__ hin_g, u16* __restrict__ hout_g,
        const u16* __restrict__ Wc, const u16* __restrict__ Wh, const float* __restrict__ bias,
        const float* __restrict__ sb1, const float* __restrict__ sw2, const float* __restrict__ sb2,
        const float* __restrict__ gs, int* __restrict__ softex, const int* __restrict__ hardex,
        float* __restrict__ outP) {
    __shared__ u32 hin[16 * 64];                // swizzled gathered tile (u32 = 2 bf16)
    __shared__ u16 hl[16 * HH];                 // swizzled h tile for GEMM2
    __shared__ float l0s[2][16], l1s[2][16];
    __shared__ int hx[16];
    int tid = threadIdx.x;
    int wave = tid >> 6, lane = tid & 63;
    int row0 = blockIdx.x * 16;
    if (tid < 16) hx[tid] = hardex[row0 + tid];
    // ---- phase 1: gather 4 nodes per wave into swizzled LDS ----
    #pragma unroll
    for (int i = 0; i < 4; ++i) {
        int row = wave * 4 + i;
        int node = row0 + row;
        int beg = irow[node], end = irow[node + 1];
        float dvd = dinv[node];
        float a0 = 0.f, a1 = 0.f;
        int e = beg;
        for (; e + 3 < end; e += 4) {
            int s0 = csrc[e], s1 = csrc[e + 1], s2 = csrc[e + 2], s3 = csrc[e + 3];
            float n0 = dinv[s0], n1 = dinv[s1], n2 = dinv[s2], n3 = dinv[s3];
            u32 w0 = *(const u32*)(hin_g + (size_t)s0 * HH + lane * 2);
            u32 w1 = *(const u32*)(hin_g + (size_t)s1 * HH + lane * 2);
            u32 w2 = *(const u32*)(hin_g + (size_t)s2 * HH + lane * 2);
            u32 w3 = *(const u32*)(hin_g + (size_t)s3 * HH + lane * 2);
            a0 = fmaf(n0, blo(w0), a0); a1 = fmaf(n0, bhi(w0), a1);
            a0 = fmaf(n1, blo(w1), a0); a1 = fmaf(n1, bhi(w1), a1);
            a0 = fmaf(n2, blo(w2), a0); a1 = fmaf(n2, bhi(w2), a1);
            a0 = fmaf(n3, blo(w3), a0); a1 = fmaf(n3, bhi(w3), a1);
        }
        for (; e < end; ++e) {
            int s0 = csrc[e];
            float n0 = dinv[s0];
            u32 w0 = *(const u32*)(hin_g + (size_t)s0 * HH + lane * 2);
            a0 = fmaf(n0, blo(w0), a0); a1 = fmaf(n0, bhi(w0), a1);
        }
        a0 *= dvd; a1 *= dvd;
        u32 hw = *(const u32*)(hin_g + (size_t)node * HH + lane * 2);
        float self = dvd * dvd;                 // self-loop norm (ref gcn_norm)
        a0 = fmaf(blo(hw), self, a0);
        a1 = fmaf(bhi(hw), self, a1);
        hin[row * 64 + (((lane >> 2) ^ (row & 7)) << 2) + (lane & 3)] =
            (u32)f2b(a0) | ((u32)f2b(a1) << 16);
    }
    __syncthreads();
    // ---- phase 2: GEMM1 (conv) ----
    int r = lane & 15, g = lane >> 4;
    const u16* hinw = (const u16*)hin;
    s16x8 af[4];
    #pragma unroll
    for (int kk = 0; kk < 4; ++kk) {
        int chunk = (kk * 4 + g) ^ (r & 7);
        af[kk] = *(const s16x8*)(hinw + r * HH + chunk * 8);
    }
    f32x4 acc[2];
    #pragma unroll
    for (int cc = 0; cc < 2; ++cc) {
        int c0 = wave * 32 + cc * 16;
        const u16* brow = Wc + (size_t)(c0 + r) * HH;
        f32x4 a = {0.f, 0.f, 0.f, 0.f};
        #pragma unroll
        for (int kk = 0; kk < 4; ++kk) {
            s16x8 b = *(const s16x8*)(brow + kk * 32 + g * 8);
            a = __builtin_amdgcn_mfma_f32_16x16x32_bf16(af[kk], b, a, 0, 0, 0);
        }
        acc[cc] = a;
    }
    #pragma unroll
    for (int cc = 0; cc < 2; ++cc) {
        int col = wave * 32 + cc * 16 + r;
        float bv = bias[col];
        #pragma unroll
        for (int j = 0; j < 4; ++j) {
            int row = g * 4 + j;
            float v = acc[cc][j] + bv;
            if (geluf) v = 0.5f * v * (1.0f + erff(v * 0.70710678118654752f));
            stbf(hout_g, (size_t)(row0 + row) * HH + col, v);
            int chunk = (col >> 3) ^ (row & 7);            // XOR swizzle (G4)
            hl[row * HH + chunk * 8 + (col & 7)] = f2b(v);
        }
    }
    __syncthreads();
    // ---- phase 3: GEMM2 (heads) ----
    #pragma unroll
    for (int kk = 0; kk < 4; ++kk) {
        int k0 = kk * 32 + g * 8;
        int chunk = (k0 >> 3) ^ (r & 7);
        af[kk] = *(const s16x8*)(hl + r * HH + chunk * 8);
    }
    #pragma unroll
    for (int cc = 0; cc < 2; ++cc) {
        int c0 = wave * 32 + cc * 16;
        const u16* brow = Wh + (size_t)(c0 + r) * HH;
        f32x4 a = {0.f, 0.f, 0.f, 0.f};
        #pragma unroll
        for (int kk = 0; kk < 4; ++kk) {
            s16x8 b = *(const s16x8*)(brow + kk * 32 + g * 8);
            a = __builtin_amdgcn_mfma_f32_16x16x32_bf16(af[kk], b, a, 0, 0, 0);
        }
        acc[cc] = a;
    }
    if (wave < 2) {
        // soft half (cols 0..63): in-register hidden + logit partials
        float pl0[4] = {0.f, 0.f, 0.f, 0.f}, pl1[4] = {0.f, 0.f, 0.f, 0.f};
        #pragma unroll
        for (int cc = 0; cc < 2; ++cc) {
            int col = wave * 32 + cc * 16 + r;
            float b1 = sb1[col], w20 = sw2[col * 2], w21 = sw2[col * 2 + 1];
            #pragma unroll
            for (int j = 0; j < 4; ++j) {
                float hv = fmaxf(acc[cc][j] + b1, 0.f);
                pl0[j] = fmaf(hv, w20, pl0[j]);
                pl1[j] = fmaf(hv, w21, pl1[j]);
            }
        }
        #pragma unroll
        for (int off = 1; off < 16; off <<= 1) {
            #pragma unroll
            for (int j = 0; j < 4; ++j) {
                pl0[j] += __shfl_xor(pl0[j], off);
                pl1[j] += __shfl_xor(pl1[j], off);
            }
        }
        if (r == 0) {
            #pragma unroll
            for (int j = 0; j < 4; ++j) {
                l0s[wave][g * 4 + j] = pl0[j];
                l1s[wave][g * 4 + j] = pl1[j];
            }
        }
    } else {
        // hard half (cols 64..127): f32 P into out z-region, only for not-yet-exited rows
        #pragma unroll
        for (int cc = 0; cc < 2; ++cc) {
            int col = wave * 32 + cc * 16 + r;
            #pragma unroll
            for (int j = 0; j < 4; ++j) {
                int row = g * 4 + j;
                if (!hx[row]) outP[(size_t)(row0 + row) * HH + col] = acc[cc][j];
            }
        }
    }
    __syncthreads();
    if (tid < 16) {
        int n = row0 + tid;
        float l0 = l0s[0][tid] + l0s[1][tid] + sb2[0];
        float l1 = l1s[0][tid] + l1s[1][tid] + sb2[1];
        const float* gg = gs + ((size_t)li * NN + n) * 2;
        if (l1 + gg[1] > l0 + gg[0]) softex[n] = 1;
    }
}

// ---- hard finish: readiness gather over out-CSR; P read f32 from out z-region ----
__global__ __launch_bounds__(256) void hard_fin_k(int li,
        const u16* __restrict__ h, const float* __restrict__ hw1, const float* __restrict__ hb1,
        const float* __restrict__ hw2, const float* __restrict__ hb2,
        const float* __restrict__ gh, const int* __restrict__ softex,
        int* __restrict__ hardex, int* __restrict__ exitl,
        const int* __restrict__ orow, const u16* __restrict__ ocol,
        float* __restrict__ out) {
    int t = threadIdx.x;
    int n = blockIdx.x * 4 + (t >> 6);
    int j = t & 63;
    if (!softex[n] || hardex[n]) return;   // wave-uniform; non-soft-exited never hard-exit (1e6 margin)
    int ob = orow[n], oe = orow[n + 1];
    int cnt = 0;
    for (int e = ob + j; e < oe; e += 64) cnt += softex[ocol[e]];
    #pragma unroll
    for (int off = 32; off > 0; off >>= 1) cnt += __shfl_xor(cnt, off);
    int dns = oe - ob; if (dns < 1) dns = 1;
    float r = (float)cnt / (float)dns;
    float pv = out[(size_t)n * HH + CHH + j];
    float hid = fmaxf(pv + r * hw1[HH * CHH + j] + hb1[j], 0.f);
    float l0 = hid * hw2[j * 2], l1 = hid * hw2[j * 2 + 1];
    #pragma unroll
    for (int off = 32; off > 0; off >>= 1) {
        l0 += __shfl_xor(l0, off);   // butterfly: identical sums on all lanes
        l1 += __shfl_xor(l1, off);
    }
    const float* g = gh + ((size_t)li * NN + n) * 2;
    if (l1 + hb2[1] + g[1] > l0 + hb2[0] + g[0]) {
        if (j == 0) { hardex[n] = 1; exitl[n] = li; }
        u32 hw = *(const u32*)(h + (size_t)n * HH + j * 2);
        out[(size_t)n * HH + j * 2]     = blo(hw);
        out[(size_t)n * HH + j * 2 + 1] = bhi(hw);
    }
}

// ---- tail: non-exited z rows + exit_layers; per-block exit histogram -> act ----
__global__ __launch_bounds__(256) void tail_k(const u16* __restrict__ h, const int* __restrict__ exitl,
        float* __restrict__ out, int* __restrict__ act) {
    __shared__ int c[LL];
    int t = threadIdx.x;
    int i = blockIdx.x * 256 + t;
    if (t < LL) c[t] = 0;
    __syncthreads();
    if (i < ZT) {
        int n = i >> 7;
        if (exitl[n] == LL) out[i] = ldbf(h, (size_t)i);
    } else if (i < ZT + NN) {
        int e = exitl[i - ZT];
        out[i] = (float)e;
        if (e < LL) atomicAdd(&c[e], 1);
    }
    __syncthreads();
    if (t < LL && c[t]) atomicAdd(&act[t], c[t]);
}

// ---- finalize active counts ----
__global__ __launch_bounds__(64) void finalize_k(const int* __restrict__ act, float* __restrict__ out) {
    if (threadIdx.x == 0) {
        out[ZT + NN]     = (float)NN;
        out[ZT + NN + 1] = (float)(NN - act[0]);
        out[ZT + NN + 2] = (float)(NN - act[0] - act[1]);
    }
}

extern "C" void kernel_launch(void* const* d_in, const int* in_sizes, int n_in,
                              void* d_out, int out_size, void* d_ws, size_t ws_size,
                              hipStream_t stream) {
    float* out = (float*)d_out;                 // output is FLOAT32
    const int OUT_N = ZT + NN + LL;

    static const int CANON[19] = {6400000,1600000,300000,300000,16384,128,16384,128,16384,128,
                                  8192,64,128,2,8256,64,128,2,128};
    static const int SORTED_ROLE[19] = {5,7,9,4,6,8,1,3,2,15,17,14,16,11,13,10,12,18,0};
    int perm[19];
    bool ok = (n_in == 19);
    if (ok) {
        bool mc = true, mr = true, ms = true;
        for (int i = 0; i < 19; ++i) {
            if (in_sizes[i] != CANON[i]) mc = false;
            if (in_sizes[i] != CANON[18 - i]) mr = false;
            if (in_sizes[i] != CANON[SORTED_ROLE[i]]) ms = false;
        }
        if (mc)      for (int c = 0; c < 19; ++c) perm[c] = c;
        else if (mr) for (int c = 0; c < 19; ++c) perm[c] = 18 - c;
        else if (ms) { for (int p = 0; p < 19; ++p) perm[SORTED_ROLE[p]] = p; }
        else         for (int c = 0; c < 19; ++c) perm[c] = c;
    }
    if (!ok) {
        zero_out_k<<<(OUT_N + 255) / 256, 256, 0, stream>>>(out, OUT_N);
        return;
    }

    const float* x  = (const float*)d_in[perm[0]];
    const int*   ei = (const int*)d_in[perm[1]];
    const float* gs = (const float*)d_in[perm[2]];
    const float* gh = (const float*)d_in[perm[3]];
    const float* cw[3] = { (const float*)d_in[perm[4]], (const float*)d_in[perm[6]], (const float*)d_in[perm[8]] };
    const float* cb[3] = { (const float*)d_in[perm[5]], (const float*)d_in[perm[7]], (const float*)d_in[perm[9]] };
    const float* sw1 = (const float*)d_in[perm[10]];
    const float* sb1 = (const float*)d_in[perm[11]];
    const float* sw2 = (const float*)d_in[perm[12]];
    const float* sb2 = (const float*)d_in[perm[13]];
    const float* hw1 = (const float*)d_in[perm[14]];
    const float* hb1 = (const float*)d_in[perm[15]];
    const float* hw2 = (const float*)d_in[perm[16]];
    const float* hb2 = (const float*)d_in[perm[17]];
    // temp_w unused: temp>0 always; softmax monotone -> decisions unaffected

    const size_t H_B    = (size_t)ZT * 2;      // 12.8 MB
    const size_t FLAG_B = 200192;
    const size_t ACT_B  = 256;
    const size_t RP_B   = 200704;              // 50001 ints padded
    const size_t CE_B   = (size_t)EE * 2;      // u16 CSR payloads
    const size_t WT_B   = 4 * HH * HH * 2;
    const size_t need = 2 * H_B + 4 * FLAG_B + ACT_B + 2 * RP_B + 2 * CE_B + WT_B;  // ~30.1 MB
    if (ws_size < need) {
        zero_out_k<<<(OUT_N + 255) / 256, 256, 0, stream>>>(out, OUT_N);
        return;
    }

    char* p = (char*)d_ws;
    u16* hA   = (u16*)p; p += H_B;
    u16* hB   = (u16*)p; p += H_B;             // sort scratch lives here pre-layers
    int* softex = (int*)p; p += FLAG_B;
    int* hardex = (int*)p; p += FLAG_B;
    int* exitl  = (int*)p; p += FLAG_B;
    float* dinv = (float*)p; p += FLAG_B;
    int* act    = (int*)p; p += ACT_B;
    int* irow   = (int*)p; p += RP_B;
    int* orow   = (int*)p; p += RP_B;
    u16* csrc   = (u16*)p; p += CE_B;
    u16* ocol   = (u16*)p; p += CE_B;
    u16* wt     = (u16*)p; p += WT_B;

    // sort scratch aliased into hB (dead until layer-0 GEMM writes hB)
    char* q = (char*)hB;
    u32* ebuf1  = (u32*)q;  q += (size_t)EE * 4;
    u32* ebuf2  = (u32*)q;  q += (size_t)EE * 4;
    int* hist1  = (int*)q;  q += 256 * NBK * 4;
    int* hist2  = (int*)q;  q += 256 * NBK * 4;
    int* boffs1 = (int*)q;  q += NBK * 256 * 4;
    int* boffs2 = (int*)q;  q += NBK * 256 * 4;
    int* bstart1 = (int*)q; q += 1024;
    int* bstart2 = (int*)q; q += 1024;

    init_k<<<(ZT + 255) / 256, 256, 0, stream>>>(x, hA, softex, hardex, exitl, act);

    hist_both_k<<<256, 256, 0, stream>>>(ei, hist1, hist2);
    boffs_k<<<1, 256, 0, stream>>>(hist1, boffs1, bstart1);
    boffs_k<<<1, 256, 0, stream>>>(hist2, boffs2, bstart2);
    scat_both_k<<<256, 256, 0, stream>>>(ei, boffs1, ebuf1, boffs2, ebuf2);
    fine2_k<<<2 * NBK, 256, 0, stream>>>(ebuf1, bstart1, irow, csrc, dinv,
                                         ebuf2, bstart2, orow, ocol);
    pack_w_k<<<(4 * HH * HH + 255) / 256, 256, 0, stream>>>(cw[0], cw[1], cw[2], sw1, hw1, wt);

    u16* hbuf[2] = { hA, hB };
    for (int li = 0; li < LL; ++li) {
        int geluf = (li < LL - 1) ? 1 : 0;
        u16* hin  = hbuf[li & 1];
        u16* hout = hbuf[(li & 1) ^ 1];
        mega_k<<<NN / 16, 256, 0, stream>>>(li, geluf, irow, csrc, dinv, hin, hout,
                                            wt + (size_t)li * HH * HH, wt + (size_t)3 * HH * HH,
                                            cb[li], sb1, sw2, sb2, gs, softex, hardex, out);
        hard_fin_k<<<NN / 4, 256, 0, stream>>>(li, hout, hw1, hb1, hw2, hb2, gh, softex,
                                               hardex, exitl, orow, ocol, out);
    }
    tail_k<<<(OUT_N + 255) / 256, 256, 0, stream>>>(hbuf[LL & 1], exitl, out, act);
    finalize_k<<<1, 64, 0, stream>>>(act, out);
}